// Round 17
// baseline (686.594 us; speedup 1.0000x reference)
//
#include <hip/hip_runtime.h>

#define BATCH 8192

typedef __bf16 bf16x8 __attribute__((ext_vector_type(8)));
typedef float f32x4 __attribute__((ext_vector_type(4)));

__device__ __forceinline__ float leakyf(float x) { return x > 0.f ? x : 0.01f * x; }

__device__ __forceinline__ short f2bf(float f) {
    union { float f; unsigned u; } v; v.f = f;
    unsigned r = v.u + 0x7fffu + ((v.u >> 16) & 1u);  // RNE
    return (short)(r >> 16);
}
__device__ __forceinline__ float bf2f(short s) {
    union { unsigned u; float f; } v; v.u = ((unsigned)(unsigned short)s) << 16;
    return v.f;
}

// ---------------------------------------------------------------------------
// transpose + fp32->bf16 convert: out[c*ldo + r] = bf16(in[r*C + c])
// ---------------------------------------------------------------------------
__global__ __launch_bounds__(256) void transconv_k(const float* __restrict__ in,
                                                   short* __restrict__ out,
                                                   int R, int C, int ldo) {
    __shared__ float t[32][33];
    const int r0 = blockIdx.y * 32, c0 = blockIdx.x * 32;
    const int tx = threadIdx.x, ty = threadIdx.y;
#pragma unroll
    for (int i = 0; i < 4; ++i)
        t[ty * 4 + i][tx] = in[(size_t)(r0 + ty * 4 + i) * C + c0 + tx];
    __syncthreads();
#pragma unroll
    for (int i = 0; i < 4; ++i)
        out[(size_t)(c0 + ty * 4 + i) * ldo + r0 + tx] = f2bf(t[tx][ty * 4 + i]);
}

// ---------------------------------------------------------------------------
// MoE weight transpose with row permutation for the grouped-A' layout
// ---------------------------------------------------------------------------
__global__ __launch_bounds__(256) void transconv_moe_k(const float* __restrict__ in,
                                                       short* __restrict__ out, int C) {
    __shared__ float t[32][33];
    const int r0 = blockIdx.y * 32, c0 = blockIdx.x * 32;
    const int tx = threadIdx.x, ty = threadIdx.y;
#pragma unroll
    for (int i = 0; i < 4; ++i)
        t[ty * 4 + i][tx] = in[(size_t)(r0 + ty * 4 + i) * C + c0 + tx];
    __syncthreads();
    const int e = r0 / 1408, k = r0 - e * 1408;
    const int rp0 = (k < 384) ? (e * 384 + k) : (1536 + e * 1024 + (k - 384));
#pragma unroll
    for (int i = 0; i < 4; ++i)
        out[(size_t)(c0 + ty * 4 + i) * 5632 + rp0 + tx] = f2bf(t[tx][ty * 4 + i]);
}

// ---------------------------------------------------------------------------
// Pipelined GEMM (R16 structure + single-barrier iter): BM x 128 tile, BK=64,
// 512 threads = 8 waves 4Mx2N, 16x16x32 MFMA, A x3 / B x2 LDS, counted vmcnt,
// setprio, XOR(row&7) swizzle (0 conflicts).
// R17: ONE barrier per K-tile. Hazard audit: within window t, reads hit
// As[ia(t)], Bs[t&1]; writes hit Bs[(t+1)&1] (disjoint) and As[is(t)] =
// buffer of tile t-1 whose reads completed before barrier(t-1). Per-wave
// vmcnt before the barrier guarantees all of tile t+1's loads landed before
// any wave starts window t+1.
// BM=128: per-wave 32x64, 80 KB LDS -> 2 blocks/CU (4 waves/SIMD).
// EPI: 0 = +bias -> bf16   1 = +bias, leaky -> bf16
//      5 = +coeff@bias, leaky, 4 coeff-scaled bf16 copies at e*1024 (MoE)
//      6 = +coeff@bias, no act -> f32 (MoE last layer)
// ---------------------------------------------------------------------------
template <int BM, int EPI>
__global__ __launch_bounds__(512) void mm_p3(
    const short* __restrict__ A, int lda,
    const short* __restrict__ Bt, int ldb,
    const float* __restrict__ bias, const float* __restrict__ coeff,
    short* __restrict__ Cb, float* __restrict__ Cf, int ldc, int N, int K) {
    constexpr int TSZA = BM * 64;   // shorts per A buffer
    constexpr int TSZB = 128 * 64;  // shorts per B buffer (16 KB)
    constexpr int RA = BM / 64;     // stageA rounds (4 or 2) == vmcnt count
    constexpr int WMR = BM / 4;     // per-wave M rows (64 or 32)
    constexpr int FM = WMR / 16;    // a-fragments per wave (4 or 2)
    __shared__ short As[3 * TSZA];
    __shared__ short Bs[2 * TSZB];
    const int tid = threadIdx.x;
    const int wave = tid >> 6, lane = tid & 63;
    const int wm = wave >> 1, wq = wave & 1;  // 4 M-waves x 2 N-waves

    // XCD-aware swizzle (bijective when nwg%8==0)
    int bx = blockIdx.x, by = blockIdx.y;
    {
        int nwg = gridDim.x * gridDim.y;
        if ((nwg & 7) == 0) {
            int flat = by * gridDim.x + bx;
            int nf = (flat & 7) * (nwg >> 3) + (flat >> 3);
            bx = nf % gridDim.x;
            by = nf / gridDim.x;
        }
    }
    const int m0 = by * BM, n0 = bx * 128;
    const int srow = lane >> 3;                   // 0..7 within 8-row chunk
    const int scolsw = ((lane & 7) ^ srow) << 3;  // swizzled source col (shorts)
    const int l15 = lane & 15;
    const int khalf = (lane >> 4) << 3;

    auto stageA = [&](int kt, int buf) {
#pragma unroll
        for (int it = 0; it < RA; ++it) {
            int chunk = it * 8 + wave;
            int row = chunk * 8 + srow;
            const short* g = A + (size_t)(m0 + row) * lda + kt + scolsw;
            __builtin_amdgcn_global_load_lds(
                (const __attribute__((address_space(1))) void*)g,
                (__attribute__((address_space(3))) void*)(As + buf * TSZA + chunk * 512),
                16, 0, 0);
        }
    };
    auto stageB = [&](int kt, int buf) {
#pragma unroll
        for (int it = 0; it < 2; ++it) {
            int chunk = it * 8 + wave;
            int row = chunk * 8 + srow;
            const short* g = Bt + (size_t)(n0 + row) * ldb + kt + scolsw;
            __builtin_amdgcn_global_load_lds(
                (const __attribute__((address_space(1))) void*)g,
                (__attribute__((address_space(3))) void*)(Bs + buf * TSZB + chunk * 512),
                16, 0, 0);
        }
    };
    auto waitRA = [&]() {
        if constexpr (BM == 256) {
            asm volatile("s_waitcnt vmcnt(4)" ::: "memory");
        } else {
            asm volatile("s_waitcnt vmcnt(2)" ::: "memory");
        }
    };

    f32x4 acc[FM][4];
    const f32x4 z4 = {0.f, 0.f, 0.f, 0.f};
#pragma unroll
    for (int i = 0; i < FM; ++i)
#pragma unroll
        for (int j = 0; j < 4; ++j) acc[i][j] = z4;

    const int nk = K >> 6;  // all call sites have nk >= 3

    // prologue: A(0),B(0),A(1) in flight; wait A(0),B(0), leave A(1)
    stageA(0, 0);
    stageB(0, 0);
    stageA(64, 1);
    __builtin_amdgcn_sched_barrier(0);
    waitRA();
    __builtin_amdgcn_s_barrier();
    __builtin_amdgcn_sched_barrier(0);

    int ia = 0;  // A buffer holding tile t
    int is = 2;  // A buffer for tile t+2
#pragma unroll 1
    for (int t = 0; t < nk; ++t) {
        const short* Ah = As + ia * TSZA;
        const short* Bh = Bs + (t & 1) * TSZB;

        // ---- PH1 (kk=0): ds_read + stageB(t+1) -> MFMA (no barrier) ----
        {
            bf16x8 a[FM], b[4];
#pragma unroll
            for (int i = 0; i < FM; ++i) {
                int R = wm * WMR + i * 16 + l15;
                a[i] = *(const bf16x8*)&Ah[R * 64 + (khalf ^ ((R & 7) << 3))];
            }
#pragma unroll
            for (int j = 0; j < 4; ++j) {
                int R = wq * 64 + j * 16 + l15;
                b[j] = *(const bf16x8*)&Bh[R * 64 + (khalf ^ ((R & 7) << 3))];
            }
            if (t + 1 < nk) stageB((t + 1) << 6, (t + 1) & 1);
            __builtin_amdgcn_sched_barrier(0);
            __builtin_amdgcn_s_setprio(1);
#pragma unroll
            for (int i = 0; i < FM; ++i)
#pragma unroll
                for (int j = 0; j < 4; ++j)
                    acc[i][j] = __builtin_amdgcn_mfma_f32_16x16x32_bf16(
                        a[i], b[j], acc[i][j], 0, 0, 0);
            __builtin_amdgcn_s_setprio(0);
            __builtin_amdgcn_sched_barrier(0);
            // barrier removed (R17): buffer safety is carried by the
            // end-of-iter vmcnt+barrier; waves may drift within the window.
        }

        // ---- PH2 (kk=1): ds_read + stageA(t+2) -> MFMA -> vmcnt -> barrier ----
        {
            bf16x8 a[FM], b[4];
#pragma unroll
            for (int i = 0; i < FM; ++i) {
                int R = wm * WMR + i * 16 + l15;
                a[i] = *(const bf16x8*)&Ah[R * 64 + ((32 + khalf) ^ ((R & 7) << 3))];
            }
#pragma unroll
            for (int j = 0; j < 4; ++j) {
                int R = wq * 64 + j * 16 + l15;
                b[j] = *(const bf16x8*)&Bh[R * 64 + ((32 + khalf) ^ ((R & 7) << 3))];
            }
            if (t + 2 < nk) stageA((t + 2) << 6, is);
            __builtin_amdgcn_sched_barrier(0);
            __builtin_amdgcn_s_setprio(1);
#pragma unroll
            for (int i = 0; i < FM; ++i)
#pragma unroll
                for (int j = 0; j < 4; ++j)
                    acc[i][j] = __builtin_amdgcn_mfma_f32_16x16x32_bf16(
                        a[i], b[j], acc[i][j], 0, 0, 0);
            __builtin_amdgcn_s_setprio(0);
            __builtin_amdgcn_sched_barrier(0);
            if (t + 1 < nk) {
                if (t + 2 < nk) {
                    waitRA();  // A(t+1),B(t+1) landed; A(t+2) stays in flight
                } else {
                    asm volatile("s_waitcnt vmcnt(0)" ::: "memory");
                }
            }
            __builtin_amdgcn_s_barrier();  // buffer-rotation fence (required)
        }
        ia = (ia == 2) ? 0 : ia + 1;
        is = (is == 2) ? 0 : is + 1;
    }

    // epilogue: D layout col=lane&15, row=(lane>>4)*4+reg
#pragma unroll
    for (int i = 0; i < FM; ++i) {
#pragma unroll
        for (int r = 0; r < 4; ++r) {
            int row = m0 + wm * WMR + i * 16 + ((lane >> 4) << 2) + r;
#pragma unroll
            for (int j = 0; j < 4; ++j) {
                int col = n0 + wq * 64 + j * 16 + l15;
                float v = acc[i][j][r];
                if constexpr (EPI == 0) {
                    v += bias[col];
                    Cb[(size_t)row * ldc + col] = f2bf(v);
                } else if constexpr (EPI == 1) {
                    v = leakyf(v + bias[col]);
                    Cb[(size_t)row * ldc + col] = f2bf(v);
                } else if constexpr (EPI == 5) {
                    const float4 c4 = *reinterpret_cast<const float4*>(coeff + (size_t)row * 4);
                    v += c4.x * bias[col] + c4.y * bias[N + col] +
                         c4.z * bias[2 * N + col] + c4.w * bias[3 * N + col];
                    float a = leakyf(v);
                    Cb[(size_t)row * ldc + 0 * 1024 + col] = f2bf(c4.x * a);
                    Cb[(size_t)row * ldc + 1 * 1024 + col] = f2bf(c4.y * a);
                    Cb[(size_t)row * ldc + 2 * 1024 + col] = f2bf(c4.z * a);
                    Cb[(size_t)row * ldc + 3 * 1024 + col] = f2bf(c4.w * a);
                } else {  // EPI == 6
                    const float4 c4 = *reinterpret_cast<const float4*>(coeff + (size_t)row * 4);
                    v += c4.x * bias[col] + c4.y * bias[N + col] +
                         c4.z * bias[2 * N + col] + c4.w * bias[3 * N + col];
                    Cf[(size_t)row * ldc + col] = v;
                }
            }
        }
    }
}

// ---------------------------------------------------------------------------
// bf16 MFMA GEMM (kept for heads/gate/SAFE): 128-tile, BK=64, dbuf + XOR
// swizzle, 16x16x32. EPI: 1 leaky bf16; 2 heads; 3/4 MoE expert loop.
// ---------------------------------------------------------------------------
template <int BM, int BN, int EPI>
__global__ __launch_bounds__(256) void mm_k(
    const short* __restrict__ A, int lda,
    const short* __restrict__ Bt, int ldb,
    const float* __restrict__ bias, const float* __restrict__ bias2,
    const float* __restrict__ coeff,
    short* __restrict__ Cb, float* __restrict__ Cf, float* __restrict__ Cf2,
    int ldc, int N, int K) {
    constexpr bool MOE = (EPI == 3 || EPI == 4);
    constexpr int WM = BM / 2, WN = BN / 2;
    constexpr int FM = WM / 16, FN = WN / 16;
    constexpr int ASZ = BM * 64, BSZ = BN * 64;
    __shared__ short As[2 * ASZ];
    __shared__ short Bs[2 * BSZ];
    const int tid = threadIdx.x;
    const int wave = tid >> 6, lane = tid & 63;
    const int wm = wave >> 1, wq = wave & 1;

    int bx = blockIdx.x, by = blockIdx.y;
    {
        int nwg = gridDim.x * gridDim.y;
        if ((nwg & 7) == 0) {
            int flat = by * gridDim.x + bx;
            int nf = (flat & 7) * (nwg >> 3) + (flat >> 3);
            bx = nf % gridDim.x;
            by = nf / gridDim.x;
        }
    }
    const int m0 = by * BM, n0 = bx * BN;
    const int srow = lane >> 3;
    const int scolsw = ((lane & 7) ^ srow) << 3;
    const int l15 = lane & 15;
    const int khalf = (lane >> 4) << 3;

    auto stage = [&](const short* Bsrc, int kt, int half) {
#pragma unroll
        for (int it = 0; it < BM / 32; ++it) {
            int chunk = it * 4 + wave;
            int row = chunk * 8 + srow;
            const short* g = A + (size_t)(m0 + row) * lda + kt + scolsw;
            __builtin_amdgcn_global_load_lds(
                (const __attribute__((address_space(1))) void*)g,
                (__attribute__((address_space(3))) void*)(As + half * ASZ + chunk * 512),
                16, 0, 0);
        }
#pragma unroll
        for (int it = 0; it < BN / 32; ++it) {
            int chunk = it * 4 + wave;
            int row = chunk * 8 + srow;
            const short* g = Bsrc + (size_t)(n0 + row) * ldb + kt + scolsw;
            __builtin_amdgcn_global_load_lds(
                (const __attribute__((address_space(1))) void*)g,
                (__attribute__((address_space(3))) void*)(Bs + half * BSZ + chunk * 512),
                16, 0, 0);
        }
    };

    f32x4 acc[FM][FN];
    f32x4 accf[MOE ? FM : 1][MOE ? FN : 1];
    const f32x4 z4 = {0.f, 0.f, 0.f, 0.f};
    if constexpr (MOE) {
#pragma unroll
        for (int i = 0; i < FM; ++i)
#pragma unroll
            for (int j = 0; j < FN; ++j) accf[i][j] = z4;
    }

    constexpr int NE = MOE ? 4 : 1;
    const int nk = K >> 6;
#pragma unroll 1
    for (int e = 0; e < NE; ++e) {
        const short* Be = Bt + (size_t)e * K;
#pragma unroll
        for (int i = 0; i < FM; ++i)
#pragma unroll
            for (int j = 0; j < FN; ++j) acc[i][j] = z4;

        stage(Be, 0, 0);
        __syncthreads();

#pragma unroll 1
        for (int t = 0; t < nk; ++t) {
            const int cur = t & 1;
            if (t + 1 < nk) stage(Be, (t + 1) << 6, cur ^ 1);
            const short* Ah = As + cur * ASZ;
            const short* Bh = Bs + cur * BSZ;
#pragma unroll
            for (int kk = 0; kk < 2; ++kk) {
                bf16x8 a[FM], b[FN];
#pragma unroll
                for (int i = 0; i < FM; ++i) {
                    int R = wm * WM + i * 16 + l15;
                    int off = (kk * 32 + khalf) ^ ((R & 7) << 3);
                    a[i] = *(const bf16x8*)&Ah[R * 64 + off];
                }
#pragma unroll
                for (int j = 0; j < FN; ++j) {
                    int R = wq * WN + j * 16 + l15;
                    int off = (kk * 32 + khalf) ^ ((R & 7) << 3);
                    b[j] = *(const bf16x8*)&Bh[R * 64 + off];
                }
#pragma unroll
                for (int i = 0; i < FM; ++i)
#pragma unroll
                    for (int j = 0; j < FN; ++j)
                        acc[i][j] = __builtin_amdgcn_mfma_f32_16x16x32_bf16(
                            a[i], b[j], acc[i][j], 0, 0, 0);
            }
            __syncthreads();
        }
        if constexpr (MOE) {
#pragma unroll
            for (int i = 0; i < FM; ++i) {
                int rbase = m0 + wm * WM + i * 16 + ((lane >> 4) << 2);
#pragma unroll
                for (int r = 0; r < 4; ++r) {
                    float ce = coeff[(size_t)(rbase + r) * 4 + e];
#pragma unroll
                    for (int j = 0; j < FN; ++j) accf[i][j][r] += ce * acc[i][j][r];
                }
            }
        }
    }

#pragma unroll
    for (int i = 0; i < FM; ++i) {
#pragma unroll
        for (int r = 0; r < 4; ++r) {
            int row = m0 + wm * WM + i * 16 + ((lane >> 4) << 2) + r;
#pragma unroll
            for (int j = 0; j < FN; ++j) {
                int col = n0 + wq * WN + j * 16 + l15;
                float v = MOE ? accf[i][j][r] : acc[i][j][r];
                if constexpr (EPI == 0) {
                    v += bias[col];
                    Cb[(size_t)row * ldc + col] = f2bf(v);
                } else if constexpr (EPI == 1) {
                    v = leakyf(v + bias[col]);
                    Cb[(size_t)row * ldc + col] = f2bf(v);
                } else if constexpr (EPI == 2) {
                    if (col < 128) {
                        Cf[(size_t)row * 128 + col] = v + bias[col];
                    } else {
                        float u = v + bias2[col - 128];
                        u = fminf(fmaxf(u, -5.f), 5.f);
                        Cf2[(size_t)row * 128 + (col - 128)] = u;
                    }
                } else if constexpr (EPI == 3) {
                    const float* c4 = coeff + (size_t)row * 4;
                    v += c4[0] * bias[col] + c4[1] * bias[N + col] +
                         c4[2] * bias[2 * N + col] + c4[3] * bias[3 * N + col];
                    Cb[(size_t)row * ldc + col] = f2bf(leakyf(v));
                } else {  // EPI == 4
                    const float* c4 = coeff + (size_t)row * 4;
                    v += c4[0] * bias[col] + c4[1] * bias[N + col] +
                         c4[2] * bias[2 * N + col] + c4[3] * bias[3 * N + col];
                    Cf[(size_t)row * ldc + col] = v;
                }
            }
        }
    }
}

// ---------------------------------------------------------------------------
// normalize + scatter bf16 into cat buffers
// ---------------------------------------------------------------------------
__global__ __launch_bounds__(256) void norm_k(
    const float* __restrict__ x, const float* __restrict__ w,
    const float* __restrict__ im, const float* __restrict__ iv,
    const float* __restrict__ cm, const float* __restrict__ cv,
    short* __restrict__ enc0, short* __restrict__ encA,
    short* __restrict__ encB, short* __restrict__ dec0) {
    int idx = blockIdx.x * 256 + threadIdx.x;
    const int TX = BATCH * 512;
    if (idx < TX) {
        int b = idx >> 9, j = idx & 511;
        float v = (x[idx] - im[j]) * rsqrtf(iv[j] + 1e-4f);
        v = fminf(fmaxf(v, -5.f), 5.f);
        enc0[(size_t)b * 768 + j] = f2bf(v);
    } else {
        int k = idx - TX;
        if (k < BATCH * 256) {
            int b = k >> 8, j = k & 255;
            float v = (w[k] - cm[j]) * rsqrtf(cv[j] + 1e-4f);
            if (v != v) v = 0.f;  // isnan -> 0 (wn only)
            v = fminf(fmaxf(v, -5.f), 5.f);
            short s = f2bf(v);
            enc0[(size_t)b * 768 + 512 + j] = s;
            encA[(size_t)b * 1280 + j] = s;
            encB[(size_t)b * 1280 + j] = s;
            dec0[(size_t)b * 384 + 128 + j] = s;
        }
    }
}

__global__ __launch_bounds__(256) void reparam_k(
    const float* __restrict__ mu, const float* __restrict__ lv,
    const float* __restrict__ eps, float* __restrict__ z, short* __restrict__ dec0) {
    int idx = blockIdx.x * 256 + threadIdx.x;
    if (idx >= BATCH * 128) return;
    float zv = mu[idx] + eps[idx] * expf(0.5f * lv[idx]);
    z[idx] = zv;
    int b = idx >> 7, j = idx & 127;
    dec0[(size_t)b * 384 + j] = f2bf(zv);
}

__global__ __launch_bounds__(256) void fill_zc_k(const short* __restrict__ dec0,
                                                 const float* __restrict__ cf,
                                                 short* __restrict__ dA,
                                                 short* __restrict__ dB) {
    int idx = blockIdx.x * 256 + threadIdx.x;
    if (idx >= BATCH * 1536) return;
    int b = idx / 1536, c = idx - b * 1536;
    int e = c / 384, k = c - e * 384;
    short s = f2bf(cf[(size_t)b * 4 + e] * bf2f(dec0[(size_t)b * 384 + k]));
    dA[(size_t)b * 5632 + c] = s;
    dB[(size_t)b * 5632 + c] = s;
}

__global__ __launch_bounds__(256) void fill_dec_k(const short* __restrict__ dec0,
                                                  short* __restrict__ decA,
                                                  short* __restrict__ decB) {
    int idx = blockIdx.x * 256 + threadIdx.x;
    if (idx >= BATCH * 384) return;
    int b = idx / 384, c = idx - b * 384;
    short s = dec0[idx];
    decA[(size_t)b * 1408 + c] = s;
    decB[(size_t)b * 1408 + c] = s;
}

__global__ __launch_bounds__(256) void gate_sm_k(const short* __restrict__ g1,
                                                 const float* __restrict__ w2,
                                                 const float* __restrict__ b2,
                                                 float* __restrict__ coeff) {
    int r = blockIdx.x * 256 + threadIdx.x;
    if (r >= BATCH) return;
    float l0 = b2[0], l1 = b2[1], l2 = b2[2], l3 = b2[3];
    const short* row = g1 + (size_t)r * 64;
#pragma unroll
    for (int k = 0; k < 64; ++k) {
        float gv = bf2f(row[k]);
        l0 += gv * w2[k * 4 + 0];
        l1 += gv * w2[k * 4 + 1];
        l2 += gv * w2[k * 4 + 2];
        l3 += gv * w2[k * 4 + 3];
    }
    float mx = fmaxf(fmaxf(l0, l1), fmaxf(l2, l3));
    float e0 = expf(l0 - mx), e1 = expf(l1 - mx), e2 = expf(l2 - mx), e3 = expf(l3 - mx);
    float s = 1.f / (e0 + e1 + e2 + e3);
    float4 outv = make_float4(e0 * s, e1 * s, e2 * s, e3 * s);
    *reinterpret_cast<float4*>(coeff + (size_t)r * 4) = outv;
}

extern "C" void kernel_launch(void* const* d_in, const int* in_sizes, int n_in,
                              void* d_out, int out_size, void* d_ws, size_t ws_size,
                              hipStream_t stream) {
    const float* x    = (const float*)d_in[0];
    const float* w    = (const float*)d_in[1];
    const float* epsv = (const float*)d_in[2];
    const float* rim  = (const float*)d_in[3];
    const float* riv  = (const float*)d_in[4];
    const float* rcm  = (const float*)d_in[5];
    const float* rcv  = (const float*)d_in[6];
    const float* ew0 = (const float*)d_in[7];  const float* eb0 = (const float*)d_in[8];
    const float* ew1 = (const float*)d_in[9];  const float* eb1 = (const float*)d_in[10];
    const float* ew2 = (const float*)d_in[11]; const float* eb2 = (const float*)d_in[12];
    const float* ew3 = (const float*)d_in[13]; const float* eb3 = (const float*)d_in[14];
    const float* muw = (const float*)d_in[15]; const float* mub = (const float*)d_in[16];
    const float* lvw = (const float*)d_in[17]; const float* lvb = (const float*)d_in[18];
    const float* gw0 = (const float*)d_in[19]; const float* gb0 = (const float*)d_in[20];
    const float* gw1 = (const float*)d_in[21]; const float* gb1 = (const float*)d_in[22];
    const float* gw2 = (const float*)d_in[23]; const float* gb2 = (const float*)d_in[24];
    const float* dw0 = (const float*)d_in[25]; const float* db0 = (const float*)d_in[26];
    const float* dw1 = (const float*)d_in[27]; const float* db1 = (const float*)d_in[28];
    const float* dw2 = (const float*)d_in[29]; const float* db2 = (const float*)d_in[30];
    const float* dw3 = (const float*)d_in[31]; const float* db3 = (const float*)d_in[32];
    const float* dw4 = (const float*)d_in[33]; const float* db4 = (const float*)d_in[34];

    float* out    = (float*)d_out;
    float* z_out  = out;                          // [B,128]
    float* y_out  = out + (size_t)BATCH * 128;    // [B,512]
    float* mu_out = out + (size_t)BATCH * 640;    // [B,128]
    float* lv_out = out + (size_t)BATCH * 768;    // [B,128]

    // ---- workspace carve ----
    char* cur = (char*)d_ws;
    auto alloc = [&](size_t bytes) -> char* {
        char* p = cur;
        cur += (bytes + 255) & ~(size_t)255;
        return p;
    };
    auto align256 = [](size_t b) { return (b + 255) & ~(size_t)255; };

    short* ew0t = (short*)alloc((size_t)768 * 1024 * 2);
    short* ew1t = (short*)alloc((size_t)1280 * 1024 * 2);
    short* ew2t = (short*)alloc((size_t)1280 * 1024 * 2);
    short* ew3t = (short*)alloc((size_t)1280 * 1024 * 2);
    short* hdWt = (short*)alloc((size_t)256 * 1024 * 2);   // rows 0-127 mu, 128-255 lv
    short* gw0t = (short*)alloc((size_t)64 * 384 * 2);
    short* gw1t = (short*)alloc((size_t)64 * 64 * 2);
    short* dw0t = (short*)alloc((size_t)1024 * 1536 * 2);
    short* dw1t = (short*)alloc((size_t)1024 * 5632 * 2);
    short* dw2t = (short*)alloc((size_t)1024 * 5632 * 2);
    short* dw3t = (short*)alloc((size_t)1024 * 5632 * 2);
    short* dw4t = (short*)alloc((size_t)512 * 5632 * 2);
    short* dec0 = (short*)alloc((size_t)BATCH * 384 * 2);  // [z|wn]
    short* g0   = (short*)alloc((size_t)BATCH * 64 * 2);
    short* g1   = (short*)alloc((size_t)BATCH * 64 * 2);
    float* cf   = (float*)alloc((size_t)BATCH * 4 * 4);

    char* region = cur;
    const size_t bigA = align256((size_t)BATCH * 5632 * 2);     // 92.3 MB
    const size_t fastNeed = (size_t)(region - (char*)d_ws) + 2 * bigA;
    const bool fast = (ws_size >= fastNeed);

    short* enc0 = (short*)region;                                           // [B,768]
    short* encA = (short*)(region + align256((size_t)BATCH * 768 * 2));     // [B,1280]
    short* encB = (short*)((char*)encA + align256((size_t)BATCH * 1280 * 2)); // [B,1280]
    short* hl   = encB;                                                     // [B,1024]
    short* dAp = (short*)region;
    short* dBp = (short*)(region + bigA);
    short* decA = (short*)region;                                           // [B,1408]
    short* decB = (short*)(region + align256((size_t)BATCH * 1408 * 2));    // [B,1408]

    dim3 blk(256);
    dim3 blk5(512);
    dim3 tblk(32, 8);

    // ---- weight transpose+convert ----
    transconv_k<<<dim3(1024 / 32, 768 / 32), tblk, 0, stream>>>(ew0, ew0t, 768, 1024, 768);
    transconv_k<<<dim3(1024 / 32, 1280 / 32), tblk, 0, stream>>>(ew1, ew1t, 1280, 1024, 1280);
    transconv_k<<<dim3(1024 / 32, 1280 / 32), tblk, 0, stream>>>(ew2, ew2t, 1280, 1024, 1280);
    transconv_k<<<dim3(1024 / 32, 1280 / 32), tblk, 0, stream>>>(ew3, ew3t, 1280, 1024, 1280);
    transconv_k<<<dim3(128 / 32, 1024 / 32), tblk, 0, stream>>>(muw, hdWt, 1024, 128, 1024);
    transconv_k<<<dim3(128 / 32, 1024 / 32), tblk, 0, stream>>>(lvw, hdWt + (size_t)128 * 1024, 1024, 128, 1024);
    transconv_k<<<dim3(64 / 32, 384 / 32), tblk, 0, stream>>>(gw0, gw0t, 384, 64, 384);
    transconv_k<<<dim3(64 / 32, 64 / 32), tblk, 0, stream>>>(gw1, gw1t, 64, 64, 64);
    transconv_k<<<dim3(1024 / 32, 1536 / 32), tblk, 0, stream>>>(dw0, dw0t, 1536, 1024, 1536);
    if (fast) {
        transconv_moe_k<<<dim3(1024 / 32, 5632 / 32), tblk, 0, stream>>>(dw1, dw1t, 1024);
        transconv_moe_k<<<dim3(1024 / 32, 5632 / 32), tblk, 0, stream>>>(dw2, dw2t, 1024);
        transconv_moe_k<<<dim3(1024 / 32, 5632 / 32), tblk, 0, stream>>>(dw3, dw3t, 1024);
        transconv_moe_k<<<dim3(512 / 32, 5632 / 32), tblk, 0, stream>>>(dw4, dw4t, 512);
    } else {
        transconv_k<<<dim3(1024 / 32, 5632 / 32), tblk, 0, stream>>>(dw1, dw1t, 5632, 1024, 5632);
        transconv_k<<<dim3(1024 / 32, 5632 / 32), tblk, 0, stream>>>(dw2, dw2t, 5632, 1024, 5632);
        transconv_k<<<dim3(1024 / 32, 5632 / 32), tblk, 0, stream>>>(dw3, dw3t, 5632, 1024, 5632);
        transconv_k<<<dim3(512 / 32, 5632 / 32), tblk, 0, stream>>>(dw4, dw4t, 5632, 512, 5632);
    }

    // ---- normalize into cat buffers ----
    norm_k<<<dim3(BATCH * 768 / 256), blk, 0, stream>>>(x, w, rim, riv, rcm, rcv,
                                                        enc0, encA, encB, dec0);

    // ---- encoder (BM=128, 8 waves, 2 blocks/CU = 4 waves/SIMD) ----
    dim3 gBig(1024 / 128, BATCH / 128);  // 8 x 64 = 512 blocks, 2/CU
    mm_p3<128, 0><<<gBig, blk5, 0, stream>>>(enc0, 768, ew0t, 768, eb0, nullptr,
                                             encA + 256, nullptr, 1280, 1024, 768);
    mm_p3<128, 0><<<gBig, blk5, 0, stream>>>(encA, 1280, ew1t, 1280, eb1, nullptr,
                                             encB + 256, nullptr, 1280, 1024, 1280);
    mm_p3<128, 0><<<gBig, blk5, 0, stream>>>(encB, 1280, ew2t, 1280, eb2, nullptr,
                                             encA + 256, nullptr, 1280, 1024, 1280);
    mm_p3<128, 1><<<gBig, blk5, 0, stream>>>(encA, 1280, ew3t, 1280, eb3, nullptr,
                                             hl, nullptr, 1024, 1024, 1280);

    // ---- heads: mu | clip(lv) ----
    mm_k<64, 128, 2><<<dim3(2, BATCH / 64), blk, 0, stream>>>(hl, 1024, hdWt, 1024, mub, lvb,
                                                              nullptr, nullptr, mu_out, lv_out,
                                                              0, 256, 1024);

    reparam_k<<<dim3(BATCH * 128 / 256), blk, 0, stream>>>(mu_out, lv_out, epsv, z_out, dec0);

    // ---- gate ----
    mm_k<64, 64, 1><<<dim3(1, BATCH / 64), blk, 0, stream>>>(dec0, 384, gw0t, 384, gb0, nullptr,
                                                             nullptr, g0, nullptr, nullptr,
                                                             64, 64, 384);
    mm_k<64, 64, 1><<<dim3(1, BATCH / 64), blk, 0, stream>>>(g0, 64, gw1t, 64, gb1, nullptr,
                                                             nullptr, g1, nullptr, nullptr,
                                                             64, 64, 64);
    gate_sm_k<<<dim3(BATCH / 256), blk, 0, stream>>>(g1, gw2, gb2, cf);

    if (fast) {
        // ---- FAST decoder: single-GEMM MoE layers (BM=128, 2 blocks/CU) ----
        fill_zc_k<<<dim3(BATCH * 1536 / 256), blk, 0, stream>>>(dec0, cf, dAp, dBp);
        mm_p3<128, 5><<<gBig, blk5, 0, stream>>>(dAp, 5632, dw0t, 1536, db0, cf,
                                                 dAp + 1536, nullptr, 5632, 1024, 1536);
        mm_p3<128, 5><<<gBig, blk5, 0, stream>>>(dAp, 5632, dw1t, 5632, db1, cf,
                                                 dBp + 1536, nullptr, 5632, 1024, 5632);
        mm_p3<128, 5><<<gBig, blk5, 0, stream>>>(dBp, 5632, dw2t, 5632, db2, cf,
                                                 dAp + 1536, nullptr, 5632, 1024, 5632);
        mm_p3<128, 5><<<gBig, blk5, 0, stream>>>(dAp, 5632, dw3t, 5632, db3, cf,
                                                 dBp + 1536, nullptr, 5632, 1024, 5632);
        mm_p3<128, 6><<<dim3(512 / 128, BATCH / 128), blk5, 0, stream>>>(
            dBp, 5632, dw4t, 5632, db4, cf, nullptr, y_out, 512, 512, 5632);
    } else {
        // ---- SAFE decoder: expert-loop kernels ----
        fill_dec_k<<<dim3(BATCH * 384 / 256), blk, 0, stream>>>(dec0, decA, decB);
        dim3 gDec(1024 / 128, BATCH / 128);
        mm_k<128, 128, 3><<<gDec, blk, 0, stream>>>(dec0, 384, dw0t, 1536, db0, nullptr, cf,
                                                    decA + 384, nullptr, nullptr, 1408, 1024, 384);
        mm_k<128, 128, 3><<<gDec, blk, 0, stream>>>(decA, 1408, dw1t, 5632, db1, nullptr, cf,
                                                    decB + 384, nullptr, nullptr, 1408, 1024, 1408);
        mm_k<128, 128, 3><<<gDec, blk, 0, stream>>>(decB, 1408, dw2t, 5632, db2, nullptr, cf,
                                                    decA + 384, nullptr, nullptr, 1408, 1024, 1408);
        mm_k<128, 128, 3><<<gDec, blk, 0, stream>>>(decA, 1408, dw3t, 5632, db3, nullptr, cf,
                                                    decB + 384, nullptr, nullptr, 1408, 1024, 1408);
        mm_k<128, 128, 4><<<dim3(512 / 128, BATCH / 128), blk, 0, stream>>>(
            decB, 1408, dw4t, 5632, db4, nullptr, cf, nullptr, y_out, nullptr, 512, 512, 1408);
    }
}

// Round 18
// 640.426 us; speedup vs baseline: 1.0721x; 1.0721x over previous
//
#include <hip/hip_runtime.h>

#define BATCH 8192

typedef __bf16 bf16x8 __attribute__((ext_vector_type(8)));
typedef float f32x4 __attribute__((ext_vector_type(4)));

__device__ __forceinline__ float leakyf(float x) { return x > 0.f ? x : 0.01f * x; }

__device__ __forceinline__ short f2bf(float f) {
    union { float f; unsigned u; } v; v.f = f;
    unsigned r = v.u + 0x7fffu + ((v.u >> 16) & 1u);  // RNE
    return (short)(r >> 16);
}
__device__ __forceinline__ float bf2f(short s) {
    union { unsigned u; float f; } v; v.u = ((unsigned)(unsigned short)s) << 16;
    return v.f;
}

// ---------------------------------------------------------------------------
// transpose + fp32->bf16 convert: out[c*ldo + r] = bf16(in[r*C + c])
// ---------------------------------------------------------------------------
__global__ __launch_bounds__(256) void transconv_k(const float* __restrict__ in,
                                                   short* __restrict__ out,
                                                   int R, int C, int ldo) {
    __shared__ float t[32][33];
    const int r0 = blockIdx.y * 32, c0 = blockIdx.x * 32;
    const int tx = threadIdx.x, ty = threadIdx.y;
#pragma unroll
    for (int i = 0; i < 4; ++i)
        t[ty * 4 + i][tx] = in[(size_t)(r0 + ty * 4 + i) * C + c0 + tx];
    __syncthreads();
#pragma unroll
    for (int i = 0; i < 4; ++i)
        out[(size_t)(c0 + ty * 4 + i) * ldo + r0 + tx] = f2bf(t[tx][ty * 4 + i]);
}

// ---------------------------------------------------------------------------
// MoE weight transpose with row permutation for the grouped-A' layout
// ---------------------------------------------------------------------------
__global__ __launch_bounds__(256) void transconv_moe_k(const float* __restrict__ in,
                                                       short* __restrict__ out, int C) {
    __shared__ float t[32][33];
    const int r0 = blockIdx.y * 32, c0 = blockIdx.x * 32;
    const int tx = threadIdx.x, ty = threadIdx.y;
#pragma unroll
    for (int i = 0; i < 4; ++i)
        t[ty * 4 + i][tx] = in[(size_t)(r0 + ty * 4 + i) * C + c0 + tx];
    __syncthreads();
    const int e = r0 / 1408, k = r0 - e * 1408;
    const int rp0 = (k < 384) ? (e * 384 + k) : (1536 + e * 1024 + (k - 384));
#pragma unroll
    for (int i = 0; i < 4; ++i)
        out[(size_t)(c0 + ty * 4 + i) * 5632 + rp0 + tx] = f2bf(t[tx][ty * 4 + i]);
}

// ---------------------------------------------------------------------------
// Pipelined GEMM (R16 optimum, restored): BM x 128 tile, BK=64, 512 threads =
// 8 waves 4Mx2N, 16x16x32 MFMA, A x3 / B x2 LDS, counted vmcnt, setprio,
// XOR(row&7) swizzle (0 conflicts), 2 barriers/iter. R17's 1-barrier variant
// REGRESSED 5%: the PH1 barrier staggers wave phases so ds_read and MFMA
// pipes from different waves overlap — keep it.
// BM=128: per-wave 32x64, 80 KB LDS -> 2 blocks/CU (4 waves/SIMD). All big
// GEMMs use BM=128 (TLP monotone win: 1->2->4 waves/SIMD = 17->30->35% Mfma).
// EPI: 0 = +bias -> bf16   1 = +bias, leaky -> bf16
//      5 = +coeff@bias, leaky, 4 coeff-scaled bf16 copies at e*1024 (MoE)
//      6 = +coeff@bias, no act -> f32 (MoE last layer)
// ---------------------------------------------------------------------------
template <int BM, int EPI>
__global__ __launch_bounds__(512) void mm_p3(
    const short* __restrict__ A, int lda,
    const short* __restrict__ Bt, int ldb,
    const float* __restrict__ bias, const float* __restrict__ coeff,
    short* __restrict__ Cb, float* __restrict__ Cf, int ldc, int N, int K) {
    constexpr int TSZA = BM * 64;   // shorts per A buffer
    constexpr int TSZB = 128 * 64;  // shorts per B buffer (16 KB)
    constexpr int RA = BM / 64;     // stageA rounds (4 or 2) == vmcnt count
    constexpr int WMR = BM / 4;     // per-wave M rows (64 or 32)
    constexpr int FM = WMR / 16;    // a-fragments per wave (4 or 2)
    __shared__ short As[3 * TSZA];
    __shared__ short Bs[2 * TSZB];
    const int tid = threadIdx.x;
    const int wave = tid >> 6, lane = tid & 63;
    const int wm = wave >> 1, wq = wave & 1;  // 4 M-waves x 2 N-waves

    // XCD-aware swizzle (bijective when nwg%8==0)
    int bx = blockIdx.x, by = blockIdx.y;
    {
        int nwg = gridDim.x * gridDim.y;
        if ((nwg & 7) == 0) {
            int flat = by * gridDim.x + bx;
            int nf = (flat & 7) * (nwg >> 3) + (flat >> 3);
            bx = nf % gridDim.x;
            by = nf / gridDim.x;
        }
    }
    const int m0 = by * BM, n0 = bx * 128;
    const int srow = lane >> 3;                   // 0..7 within 8-row chunk
    const int scolsw = ((lane & 7) ^ srow) << 3;  // swizzled source col (shorts)
    const int l15 = lane & 15;
    const int khalf = (lane >> 4) << 3;

    auto stageA = [&](int kt, int buf) {
#pragma unroll
        for (int it = 0; it < RA; ++it) {
            int chunk = it * 8 + wave;
            int row = chunk * 8 + srow;
            const short* g = A + (size_t)(m0 + row) * lda + kt + scolsw;
            __builtin_amdgcn_global_load_lds(
                (const __attribute__((address_space(1))) void*)g,
                (__attribute__((address_space(3))) void*)(As + buf * TSZA + chunk * 512),
                16, 0, 0);
        }
    };
    auto stageB = [&](int kt, int buf) {
#pragma unroll
        for (int it = 0; it < 2; ++it) {
            int chunk = it * 8 + wave;
            int row = chunk * 8 + srow;
            const short* g = Bt + (size_t)(n0 + row) * ldb + kt + scolsw;
            __builtin_amdgcn_global_load_lds(
                (const __attribute__((address_space(1))) void*)g,
                (__attribute__((address_space(3))) void*)(Bs + buf * TSZB + chunk * 512),
                16, 0, 0);
        }
    };
    auto waitRA = [&]() {
        if constexpr (BM == 256) {
            asm volatile("s_waitcnt vmcnt(4)" ::: "memory");
        } else {
            asm volatile("s_waitcnt vmcnt(2)" ::: "memory");
        }
    };

    f32x4 acc[FM][4];
    const f32x4 z4 = {0.f, 0.f, 0.f, 0.f};
#pragma unroll
    for (int i = 0; i < FM; ++i)
#pragma unroll
        for (int j = 0; j < 4; ++j) acc[i][j] = z4;

    const int nk = K >> 6;  // all call sites have nk >= 3

    // prologue: A(0),B(0),A(1) in flight; wait A(0),B(0), leave A(1)
    stageA(0, 0);
    stageB(0, 0);
    stageA(64, 1);
    __builtin_amdgcn_sched_barrier(0);
    waitRA();
    __builtin_amdgcn_s_barrier();
    __builtin_amdgcn_sched_barrier(0);

    int ia = 0;  // A buffer holding tile t
    int is = 2;  // A buffer for tile t+2
#pragma unroll 1
    for (int t = 0; t < nk; ++t) {
        const short* Ah = As + ia * TSZA;
        const short* Bh = Bs + (t & 1) * TSZB;

        // ---- PH1 (kk=0): ds_read + stageB(t+1) -> MFMA -> barrier ----
        {
            bf16x8 a[FM], b[4];
#pragma unroll
            for (int i = 0; i < FM; ++i) {
                int R = wm * WMR + i * 16 + l15;
                a[i] = *(const bf16x8*)&Ah[R * 64 + (khalf ^ ((R & 7) << 3))];
            }
#pragma unroll
            for (int j = 0; j < 4; ++j) {
                int R = wq * 64 + j * 16 + l15;
                b[j] = *(const bf16x8*)&Bh[R * 64 + (khalf ^ ((R & 7) << 3))];
            }
            if (t + 1 < nk) stageB((t + 1) << 6, (t + 1) & 1);
            __builtin_amdgcn_sched_barrier(0);
            __builtin_amdgcn_s_setprio(1);
#pragma unroll
            for (int i = 0; i < FM; ++i)
#pragma unroll
                for (int j = 0; j < 4; ++j)
                    acc[i][j] = __builtin_amdgcn_mfma_f32_16x16x32_bf16(
                        a[i], b[j], acc[i][j], 0, 0, 0);
            __builtin_amdgcn_s_setprio(0);
            __builtin_amdgcn_sched_barrier(0);
            __builtin_amdgcn_s_barrier();  // phase stagger across waves (perf!)
        }

        // ---- PH2 (kk=1): ds_read + stageA(t+2) -> MFMA -> vmcnt -> barrier ----
        {
            bf16x8 a[FM], b[4];
#pragma unroll
            for (int i = 0; i < FM; ++i) {
                int R = wm * WMR + i * 16 + l15;
                a[i] = *(const bf16x8*)&Ah[R * 64 + ((32 + khalf) ^ ((R & 7) << 3))];
            }
#pragma unroll
            for (int j = 0; j < 4; ++j) {
                int R = wq * 64 + j * 16 + l15;
                b[j] = *(const bf16x8*)&Bh[R * 64 + ((32 + khalf) ^ ((R & 7) << 3))];
            }
            if (t + 2 < nk) stageA((t + 2) << 6, is);
            __builtin_amdgcn_sched_barrier(0);
            __builtin_amdgcn_s_setprio(1);
#pragma unroll
            for (int i = 0; i < FM; ++i)
#pragma unroll
                for (int j = 0; j < 4; ++j)
                    acc[i][j] = __builtin_amdgcn_mfma_f32_16x16x32_bf16(
                        a[i], b[j], acc[i][j], 0, 0, 0);
            __builtin_amdgcn_s_setprio(0);
            __builtin_amdgcn_sched_barrier(0);
            if (t + 1 < nk) {
                if (t + 2 < nk) {
                    waitRA();  // A(t+1),B(t+1) landed; A(t+2) stays in flight
                } else {
                    asm volatile("s_waitcnt vmcnt(0)" ::: "memory");
                }
            }
            __builtin_amdgcn_s_barrier();  // buffer-rotation fence (required)
        }
        ia = (ia == 2) ? 0 : ia + 1;
        is = (is == 2) ? 0 : is + 1;
    }

    // epilogue: D layout col=lane&15, row=(lane>>4)*4+reg
#pragma unroll
    for (int i = 0; i < FM; ++i) {
#pragma unroll
        for (int r = 0; r < 4; ++r) {
            int row = m0 + wm * WMR + i * 16 + ((lane >> 4) << 2) + r;
#pragma unroll
            for (int j = 0; j < 4; ++j) {
                int col = n0 + wq * 64 + j * 16 + l15;
                float v = acc[i][j][r];
                if constexpr (EPI == 0) {
                    v += bias[col];
                    Cb[(size_t)row * ldc + col] = f2bf(v);
                } else if constexpr (EPI == 1) {
                    v = leakyf(v + bias[col]);
                    Cb[(size_t)row * ldc + col] = f2bf(v);
                } else if constexpr (EPI == 5) {
                    const float4 c4 = *reinterpret_cast<const float4*>(coeff + (size_t)row * 4);
                    v += c4.x * bias[col] + c4.y * bias[N + col] +
                         c4.z * bias[2 * N + col] + c4.w * bias[3 * N + col];
                    float a = leakyf(v);
                    Cb[(size_t)row * ldc + 0 * 1024 + col] = f2bf(c4.x * a);
                    Cb[(size_t)row * ldc + 1 * 1024 + col] = f2bf(c4.y * a);
                    Cb[(size_t)row * ldc + 2 * 1024 + col] = f2bf(c4.z * a);
                    Cb[(size_t)row * ldc + 3 * 1024 + col] = f2bf(c4.w * a);
                } else {  // EPI == 6
                    const float4 c4 = *reinterpret_cast<const float4*>(coeff + (size_t)row * 4);
                    v += c4.x * bias[col] + c4.y * bias[N + col] +
                         c4.z * bias[2 * N + col] + c4.w * bias[3 * N + col];
                    Cf[(size_t)row * ldc + col] = v;
                }
            }
        }
    }
}

// ---------------------------------------------------------------------------
// bf16 MFMA GEMM (kept for heads/gate/SAFE): 128-tile, BK=64, dbuf + XOR
// swizzle, 16x16x32. EPI: 1 leaky bf16; 2 heads; 3/4 MoE expert loop.
// ---------------------------------------------------------------------------
template <int BM, int BN, int EPI>
__global__ __launch_bounds__(256) void mm_k(
    const short* __restrict__ A, int lda,
    const short* __restrict__ Bt, int ldb,
    const float* __restrict__ bias, const float* __restrict__ bias2,
    const float* __restrict__ coeff,
    short* __restrict__ Cb, float* __restrict__ Cf, float* __restrict__ Cf2,
    int ldc, int N, int K) {
    constexpr bool MOE = (EPI == 3 || EPI == 4);
    constexpr int WM = BM / 2, WN = BN / 2;
    constexpr int FM = WM / 16, FN = WN / 16;
    constexpr int ASZ = BM * 64, BSZ = BN * 64;
    __shared__ short As[2 * ASZ];
    __shared__ short Bs[2 * BSZ];
    const int tid = threadIdx.x;
    const int wave = tid >> 6, lane = tid & 63;
    const int wm = wave >> 1, wq = wave & 1;

    int bx = blockIdx.x, by = blockIdx.y;
    {
        int nwg = gridDim.x * gridDim.y;
        if ((nwg & 7) == 0) {
            int flat = by * gridDim.x + bx;
            int nf = (flat & 7) * (nwg >> 3) + (flat >> 3);
            bx = nf % gridDim.x;
            by = nf / gridDim.x;
        }
    }
    const int m0 = by * BM, n0 = bx * BN;
    const int srow = lane >> 3;
    const int scolsw = ((lane & 7) ^ srow) << 3;
    const int l15 = lane & 15;
    const int khalf = (lane >> 4) << 3;

    auto stage = [&](const short* Bsrc, int kt, int half) {
#pragma unroll
        for (int it = 0; it < BM / 32; ++it) {
            int chunk = it * 4 + wave;
            int row = chunk * 8 + srow;
            const short* g = A + (size_t)(m0 + row) * lda + kt + scolsw;
            __builtin_amdgcn_global_load_lds(
                (const __attribute__((address_space(1))) void*)g,
                (__attribute__((address_space(3))) void*)(As + half * ASZ + chunk * 512),
                16, 0, 0);
        }
#pragma unroll
        for (int it = 0; it < BN / 32; ++it) {
            int chunk = it * 4 + wave;
            int row = chunk * 8 + srow;
            const short* g = Bsrc + (size_t)(n0 + row) * ldb + kt + scolsw;
            __builtin_amdgcn_global_load_lds(
                (const __attribute__((address_space(1))) void*)g,
                (__attribute__((address_space(3))) void*)(Bs + half * BSZ + chunk * 512),
                16, 0, 0);
        }
    };

    f32x4 acc[FM][FN];
    f32x4 accf[MOE ? FM : 1][MOE ? FN : 1];
    const f32x4 z4 = {0.f, 0.f, 0.f, 0.f};
    if constexpr (MOE) {
#pragma unroll
        for (int i = 0; i < FM; ++i)
#pragma unroll
            for (int j = 0; j < FN; ++j) accf[i][j] = z4;
    }

    constexpr int NE = MOE ? 4 : 1;
    const int nk = K >> 6;
#pragma unroll 1
    for (int e = 0; e < NE; ++e) {
        const short* Be = Bt + (size_t)e * K;
#pragma unroll
        for (int i = 0; i < FM; ++i)
#pragma unroll
            for (int j = 0; j < FN; ++j) acc[i][j] = z4;

        stage(Be, 0, 0);
        __syncthreads();

#pragma unroll 1
        for (int t = 0; t < nk; ++t) {
            const int cur = t & 1;
            if (t + 1 < nk) stage(Be, (t + 1) << 6, cur ^ 1);
            const short* Ah = As + cur * ASZ;
            const short* Bh = Bs + cur * BSZ;
#pragma unroll
            for (int kk = 0; kk < 2; ++kk) {
                bf16x8 a[FM], b[FN];
#pragma unroll
                for (int i = 0; i < FM; ++i) {
                    int R = wm * WM + i * 16 + l15;
                    int off = (kk * 32 + khalf) ^ ((R & 7) << 3);
                    a[i] = *(const bf16x8*)&Ah[R * 64 + off];
                }
#pragma unroll
                for (int j = 0; j < FN; ++j) {
                    int R = wq * WN + j * 16 + l15;
                    int off = (kk * 32 + khalf) ^ ((R & 7) << 3);
                    b[j] = *(const bf16x8*)&Bh[R * 64 + off];
                }
#pragma unroll
                for (int i = 0; i < FM; ++i)
#pragma unroll
                    for (int j = 0; j < FN; ++j)
                        acc[i][j] = __builtin_amdgcn_mfma_f32_16x16x32_bf16(
                            a[i], b[j], acc[i][j], 0, 0, 0);
            }
            __syncthreads();
        }
        if constexpr (MOE) {
#pragma unroll
            for (int i = 0; i < FM; ++i) {
                int rbase = m0 + wm * WM + i * 16 + ((lane >> 4) << 2);
#pragma unroll
                for (int r = 0; r < 4; ++r) {
                    float ce = coeff[(size_t)(rbase + r) * 4 + e];
#pragma unroll
                    for (int j = 0; j < FN; ++j) accf[i][j][r] += ce * acc[i][j][r];
                }
            }
        }
    }

#pragma unroll
    for (int i = 0; i < FM; ++i) {
#pragma unroll
        for (int r = 0; r < 4; ++r) {
            int row = m0 + wm * WM + i * 16 + ((lane >> 4) << 2) + r;
#pragma unroll
            for (int j = 0; j < FN; ++j) {
                int col = n0 + wq * WN + j * 16 + l15;
                float v = MOE ? accf[i][j][r] : acc[i][j][r];
                if constexpr (EPI == 0) {
                    v += bias[col];
                    Cb[(size_t)row * ldc + col] = f2bf(v);
                } else if constexpr (EPI == 1) {
                    v = leakyf(v + bias[col]);
                    Cb[(size_t)row * ldc + col] = f2bf(v);
                } else if constexpr (EPI == 2) {
                    if (col < 128) {
                        Cf[(size_t)row * 128 + col] = v + bias[col];
                    } else {
                        float u = v + bias2[col - 128];
                        u = fminf(fmaxf(u, -5.f), 5.f);
                        Cf2[(size_t)row * 128 + (col - 128)] = u;
                    }
                } else if constexpr (EPI == 3) {
                    const float* c4 = coeff + (size_t)row * 4;
                    v += c4[0] * bias[col] + c4[1] * bias[N + col] +
                         c4[2] * bias[2 * N + col] + c4[3] * bias[3 * N + col];
                    Cb[(size_t)row * ldc + col] = f2bf(leakyf(v));
                } else {  // EPI == 4
                    const float* c4 = coeff + (size_t)row * 4;
                    v += c4[0] * bias[col] + c4[1] * bias[N + col] +
                         c4[2] * bias[2 * N + col] + c4[3] * bias[3 * N + col];
                    Cf[(size_t)row * ldc + col] = v;
                }
            }
        }
    }
}

// ---------------------------------------------------------------------------
// normalize + scatter bf16 into cat buffers
// ---------------------------------------------------------------------------
__global__ __launch_bounds__(256) void norm_k(
    const float* __restrict__ x, const float* __restrict__ w,
    const float* __restrict__ im, const float* __restrict__ iv,
    const float* __restrict__ cm, const float* __restrict__ cv,
    short* __restrict__ enc0, short* __restrict__ encA,
    short* __restrict__ encB, short* __restrict__ dec0) {
    int idx = blockIdx.x * 256 + threadIdx.x;
    const int TX = BATCH * 512;
    if (idx < TX) {
        int b = idx >> 9, j = idx & 511;
        float v = (x[idx] - im[j]) * rsqrtf(iv[j] + 1e-4f);
        v = fminf(fmaxf(v, -5.f), 5.f);
        enc0[(size_t)b * 768 + j] = f2bf(v);
    } else {
        int k = idx - TX;
        if (k < BATCH * 256) {
            int b = k >> 8, j = k & 255;
            float v = (w[k] - cm[j]) * rsqrtf(cv[j] + 1e-4f);
            if (v != v) v = 0.f;  // isnan -> 0 (wn only)
            v = fminf(fmaxf(v, -5.f), 5.f);
            short s = f2bf(v);
            enc0[(size_t)b * 768 + 512 + j] = s;
            encA[(size_t)b * 1280 + j] = s;
            encB[(size_t)b * 1280 + j] = s;
            dec0[(size_t)b * 384 + 128 + j] = s;
        }
    }
}

__global__ __launch_bounds__(256) void reparam_k(
    const float* __restrict__ mu, const float* __restrict__ lv,
    const float* __restrict__ eps, float* __restrict__ z, short* __restrict__ dec0) {
    int idx = blockIdx.x * 256 + threadIdx.x;
    if (idx >= BATCH * 128) return;
    float zv = mu[idx] + eps[idx] * expf(0.5f * lv[idx]);
    z[idx] = zv;
    int b = idx >> 7, j = idx & 127;
    dec0[(size_t)b * 384 + j] = f2bf(zv);
}

__global__ __launch_bounds__(256) void fill_zc_k(const short* __restrict__ dec0,
                                                 const float* __restrict__ cf,
                                                 short* __restrict__ dA,
                                                 short* __restrict__ dB) {
    int idx = blockIdx.x * 256 + threadIdx.x;
    if (idx >= BATCH * 1536) return;
    int b = idx / 1536, c = idx - b * 1536;
    int e = c / 384, k = c - e * 384;
    short s = f2bf(cf[(size_t)b * 4 + e] * bf2f(dec0[(size_t)b * 384 + k]));
    dA[(size_t)b * 5632 + c] = s;
    dB[(size_t)b * 5632 + c] = s;
}

__global__ __launch_bounds__(256) void fill_dec_k(const short* __restrict__ dec0,
                                                  short* __restrict__ decA,
                                                  short* __restrict__ decB) {
    int idx = blockIdx.x * 256 + threadIdx.x;
    if (idx >= BATCH * 384) return;
    int b = idx / 384, c = idx - b * 384;
    short s = dec0[idx];
    decA[(size_t)b * 1408 + c] = s;
    decB[(size_t)b * 1408 + c] = s;
}

__global__ __launch_bounds__(256) void gate_sm_k(const short* __restrict__ g1,
                                                 const float* __restrict__ w2,
                                                 const float* __restrict__ b2,
                                                 float* __restrict__ coeff) {
    int r = blockIdx.x * 256 + threadIdx.x;
    if (r >= BATCH) return;
    float l0 = b2[0], l1 = b2[1], l2 = b2[2], l3 = b2[3];
    const short* row = g1 + (size_t)r * 64;
#pragma unroll
    for (int k = 0; k < 64; ++k) {
        float gv = bf2f(row[k]);
        l0 += gv * w2[k * 4 + 0];
        l1 += gv * w2[k * 4 + 1];
        l2 += gv * w2[k * 4 + 2];
        l3 += gv * w2[k * 4 + 3];
    }
    float mx = fmaxf(fmaxf(l0, l1), fmaxf(l2, l3));
    float e0 = expf(l0 - mx), e1 = expf(l1 - mx), e2 = expf(l2 - mx), e3 = expf(l3 - mx);
    float s = 1.f / (e0 + e1 + e2 + e3);
    float4 outv = make_float4(e0 * s, e1 * s, e2 * s, e3 * s);
    *reinterpret_cast<float4*>(coeff + (size_t)r * 4) = outv;
}

extern "C" void kernel_launch(void* const* d_in, const int* in_sizes, int n_in,
                              void* d_out, int out_size, void* d_ws, size_t ws_size,
                              hipStream_t stream) {
    const float* x    = (const float*)d_in[0];
    const float* w    = (const float*)d_in[1];
    const float* epsv = (const float*)d_in[2];
    const float* rim  = (const float*)d_in[3];
    const float* riv  = (const float*)d_in[4];
    const float* rcm  = (const float*)d_in[5];
    const float* rcv  = (const float*)d_in[6];
    const float* ew0 = (const float*)d_in[7];  const float* eb0 = (const float*)d_in[8];
    const float* ew1 = (const float*)d_in[9];  const float* eb1 = (const float*)d_in[10];
    const float* ew2 = (const float*)d_in[11]; const float* eb2 = (const float*)d_in[12];
    const float* ew3 = (const float*)d_in[13]; const float* eb3 = (const float*)d_in[14];
    const float* muw = (const float*)d_in[15]; const float* mub = (const float*)d_in[16];
    const float* lvw = (const float*)d_in[17]; const float* lvb = (const float*)d_in[18];
    const float* gw0 = (const float*)d_in[19]; const float* gb0 = (const float*)d_in[20];
    const float* gw1 = (const float*)d_in[21]; const float* gb1 = (const float*)d_in[22];
    const float* gw2 = (const float*)d_in[23]; const float* gb2 = (const float*)d_in[24];
    const float* dw0 = (const float*)d_in[25]; const float* db0 = (const float*)d_in[26];
    const float* dw1 = (const float*)d_in[27]; const float* db1 = (const float*)d_in[28];
    const float* dw2 = (const float*)d_in[29]; const float* db2 = (const float*)d_in[30];
    const float* dw3 = (const float*)d_in[31]; const float* db3 = (const float*)d_in[32];
    const float* dw4 = (const float*)d_in[33]; const float* db4 = (const float*)d_in[34];

    float* out    = (float*)d_out;
    float* z_out  = out;                          // [B,128]
    float* y_out  = out + (size_t)BATCH * 128;    // [B,512]
    float* mu_out = out + (size_t)BATCH * 640;    // [B,128]
    float* lv_out = out + (size_t)BATCH * 768;    // [B,128]

    // ---- workspace carve ----
    char* cur = (char*)d_ws;
    auto alloc = [&](size_t bytes) -> char* {
        char* p = cur;
        cur += (bytes + 255) & ~(size_t)255;
        return p;
    };
    auto align256 = [](size_t b) { return (b + 255) & ~(size_t)255; };

    short* ew0t = (short*)alloc((size_t)768 * 1024 * 2);
    short* ew1t = (short*)alloc((size_t)1280 * 1024 * 2);
    short* ew2t = (short*)alloc((size_t)1280 * 1024 * 2);
    short* ew3t = (short*)alloc((size_t)1280 * 1024 * 2);
    short* hdWt = (short*)alloc((size_t)256 * 1024 * 2);   // rows 0-127 mu, 128-255 lv
    short* gw0t = (short*)alloc((size_t)64 * 384 * 2);
    short* gw1t = (short*)alloc((size_t)64 * 64 * 2);
    short* dw0t = (short*)alloc((size_t)1024 * 1536 * 2);
    short* dw1t = (short*)alloc((size_t)1024 * 5632 * 2);
    short* dw2t = (short*)alloc((size_t)1024 * 5632 * 2);
    short* dw3t = (short*)alloc((size_t)1024 * 5632 * 2);
    short* dw4t = (short*)alloc((size_t)512 * 5632 * 2);
    short* dec0 = (short*)alloc((size_t)BATCH * 384 * 2);  // [z|wn]
    short* g0   = (short*)alloc((size_t)BATCH * 64 * 2);
    short* g1   = (short*)alloc((size_t)BATCH * 64 * 2);
    float* cf   = (float*)alloc((size_t)BATCH * 4 * 4);

    char* region = cur;
    const size_t bigA = align256((size_t)BATCH * 5632 * 2);     // 92.3 MB
    const size_t fastNeed = (size_t)(region - (char*)d_ws) + 2 * bigA;
    const bool fast = (ws_size >= fastNeed);

    short* enc0 = (short*)region;                                           // [B,768]
    short* encA = (short*)(region + align256((size_t)BATCH * 768 * 2));     // [B,1280]
    short* encB = (short*)((char*)encA + align256((size_t)BATCH * 1280 * 2)); // [B,1280]
    short* hl   = encB;                                                     // [B,1024]
    short* dAp = (short*)region;
    short* dBp = (short*)(region + bigA);
    short* decA = (short*)region;                                           // [B,1408]
    short* decB = (short*)(region + align256((size_t)BATCH * 1408 * 2));    // [B,1408]

    dim3 blk(256);
    dim3 blk5(512);
    dim3 tblk(32, 8);

    // ---- weight transpose+convert ----
    transconv_k<<<dim3(1024 / 32, 768 / 32), tblk, 0, stream>>>(ew0, ew0t, 768, 1024, 768);
    transconv_k<<<dim3(1024 / 32, 1280 / 32), tblk, 0, stream>>>(ew1, ew1t, 1280, 1024, 1280);
    transconv_k<<<dim3(1024 / 32, 1280 / 32), tblk, 0, stream>>>(ew2, ew2t, 1280, 1024, 1280);
    transconv_k<<<dim3(1024 / 32, 1280 / 32), tblk, 0, stream>>>(ew3, ew3t, 1280, 1024, 1280);
    transconv_k<<<dim3(128 / 32, 1024 / 32), tblk, 0, stream>>>(muw, hdWt, 1024, 128, 1024);
    transconv_k<<<dim3(128 / 32, 1024 / 32), tblk, 0, stream>>>(lvw, hdWt + (size_t)128 * 1024, 1024, 128, 1024);
    transconv_k<<<dim3(64 / 32, 384 / 32), tblk, 0, stream>>>(gw0, gw0t, 384, 64, 384);
    transconv_k<<<dim3(64 / 32, 64 / 32), tblk, 0, stream>>>(gw1, gw1t, 64, 64, 64);
    transconv_k<<<dim3(1024 / 32, 1536 / 32), tblk, 0, stream>>>(dw0, dw0t, 1536, 1024, 1536);
    if (fast) {
        transconv_moe_k<<<dim3(1024 / 32, 5632 / 32), tblk, 0, stream>>>(dw1, dw1t, 1024);
        transconv_moe_k<<<dim3(1024 / 32, 5632 / 32), tblk, 0, stream>>>(dw2, dw2t, 1024);
        transconv_moe_k<<<dim3(1024 / 32, 5632 / 32), tblk, 0, stream>>>(dw3, dw3t, 1024);
        transconv_moe_k<<<dim3(512 / 32, 5632 / 32), tblk, 0, stream>>>(dw4, dw4t, 512);
    } else {
        transconv_k<<<dim3(1024 / 32, 5632 / 32), tblk, 0, stream>>>(dw1, dw1t, 5632, 1024, 5632);
        transconv_k<<<dim3(1024 / 32, 5632 / 32), tblk, 0, stream>>>(dw2, dw2t, 5632, 1024, 5632);
        transconv_k<<<dim3(1024 / 32, 5632 / 32), tblk, 0, stream>>>(dw3, dw3t, 5632, 1024, 5632);
        transconv_k<<<dim3(512 / 32, 5632 / 32), tblk, 0, stream>>>(dw4, dw4t, 5632, 512, 5632);
    }

    // ---- normalize into cat buffers ----
    norm_k<<<dim3(BATCH * 768 / 256), blk, 0, stream>>>(x, w, rim, riv, rcm, rcv,
                                                        enc0, encA, encB, dec0);

    // ---- encoder (BM=128, 8 waves, 2 blocks/CU = 4 waves/SIMD) ----
    dim3 gBig(1024 / 128, BATCH / 128);  // 8 x 64 = 512 blocks, 2/CU
    mm_p3<128, 0><<<gBig, blk5, 0, stream>>>(enc0, 768, ew0t, 768, eb0, nullptr,
                                             encA + 256, nullptr, 1280, 1024, 768);
    mm_p3<128, 0><<<gBig, blk5, 0, stream>>>(encA, 1280, ew1t, 1280, eb1, nullptr,
                                             encB + 256, nullptr, 1280, 1024, 1280);
    mm_p3<128, 0><<<gBig, blk5, 0, stream>>>(encB, 1280, ew2t, 1280, eb2, nullptr,
                                             encA + 256, nullptr, 1280, 1024, 1280);
    mm_p3<128, 1><<<gBig, blk5, 0, stream>>>(encA, 1280, ew3t, 1280, eb3, nullptr,
                                             hl, nullptr, 1024, 1024, 1280);

    // ---- heads: mu | clip(lv) ----
    mm_k<64, 128, 2><<<dim3(2, BATCH / 64), blk, 0, stream>>>(hl, 1024, hdWt, 1024, mub, lvb,
                                                              nullptr, nullptr, mu_out, lv_out,
                                                              0, 256, 1024);

    reparam_k<<<dim3(BATCH * 128 / 256), blk, 0, stream>>>(mu_out, lv_out, epsv, z_out, dec0);

    // ---- gate ----
    mm_k<64, 64, 1><<<dim3(1, BATCH / 64), blk, 0, stream>>>(dec0, 384, gw0t, 384, gb0, nullptr,
                                                             nullptr, g0, nullptr, nullptr,
                                                             64, 64, 384);
    mm_k<64, 64, 1><<<dim3(1, BATCH / 64), blk, 0, stream>>>(g0, 64, gw1t, 64, gb1, nullptr,
                                                             nullptr, g1, nullptr, nullptr,
                                                             64, 64, 64);
    gate_sm_k<<<dim3(BATCH / 256), blk, 0, stream>>>(g1, gw2, gb2, cf);

    if (fast) {
        // ---- FAST decoder: single-GEMM MoE layers (BM=128, 2 blocks/CU) ----
        fill_zc_k<<<dim3(BATCH * 1536 / 256), blk, 0, stream>>>(dec0, cf, dAp, dBp);
        mm_p3<128, 5><<<gBig, blk5, 0, stream>>>(dAp, 5632, dw0t, 1536, db0, cf,
                                                 dAp + 1536, nullptr, 5632, 1024, 1536);
        mm_p3<128, 5><<<gBig, blk5, 0, stream>>>(dAp, 5632, dw1t, 5632, db1, cf,
                                                 dBp + 1536, nullptr, 5632, 1024, 5632);
        mm_p3<128, 5><<<gBig, blk5, 0, stream>>>(dBp, 5632, dw2t, 5632, db2, cf,
                                                 dAp + 1536, nullptr, 5632, 1024, 5632);
        mm_p3<128, 5><<<gBig, blk5, 0, stream>>>(dAp, 5632, dw3t, 5632, db3, cf,
                                                 dBp + 1536, nullptr, 5632, 1024, 5632);
        mm_p3<128, 6><<<dim3(512 / 128, BATCH / 128), blk5, 0, stream>>>(
            dBp, 5632, dw4t, 5632, db4, cf, nullptr, y_out, 512, 512, 5632);
    } else {
        // ---- SAFE decoder: expert-loop kernels ----
        fill_dec_k<<<dim3(BATCH * 384 / 256), blk, 0, stream>>>(dec0, decA, decB);
        dim3 gDec(1024 / 128, BATCH / 128);
        mm_k<128, 128, 3><<<gDec, blk, 0, stream>>>(dec0, 384, dw0t, 1536, db0, nullptr, cf,
                                                    decA + 384, nullptr, nullptr, 1408, 1024, 384);
        mm_k<128, 128, 3><<<gDec, blk, 0, stream>>>(decA, 1408, dw1t, 5632, db1, nullptr, cf,
                                                    decB + 384, nullptr, nullptr, 1408, 1024, 1408);
        mm_k<128, 128, 3><<<gDec, blk, 0, stream>>>(decB, 1408, dw2t, 5632, db2, nullptr, cf,
                                                    decA + 384, nullptr, nullptr, 1408, 1024, 1408);
        mm_k<128, 128, 3><<<gDec, blk, 0, stream>>>(decA, 1408, dw3t, 5632, db3, nullptr, cf,
                                                    decB + 384, nullptr, nullptr, 1408, 1024, 1408);
        mm_k<128, 128, 4><<<dim3(512 / 128, BATCH / 128), blk, 0, stream>>>(
            decB, 1408, dw4t, 5632, db4, nullptr, cf, nullptr, y_out, nullptr, 512, 512, 1408);
    }
}

// Round 19
// 613.414 us; speedup vs baseline: 1.1193x; 1.0440x over previous
//
#include <hip/hip_runtime.h>

#define BATCH 8192

typedef __bf16 bf16x8 __attribute__((ext_vector_type(8)));
typedef float f32x4 __attribute__((ext_vector_type(4)));

__device__ __forceinline__ float leakyf(float x) { return x > 0.f ? x : 0.01f * x; }

__device__ __forceinline__ short f2bf(float f) {
    union { float f; unsigned u; } v; v.f = f;
    unsigned r = v.u + 0x7fffu + ((v.u >> 16) & 1u);  // RNE
    return (short)(r >> 16);
}
__device__ __forceinline__ float bf2f(short s) {
    union { unsigned u; float f; } v; v.u = ((unsigned)(unsigned short)s) << 16;
    return v.f;
}

// ---------------------------------------------------------------------------
// transpose + fp32->bf16 convert: out[c*ldo + r] = bf16(in[r*C + c])
// ---------------------------------------------------------------------------
__global__ __launch_bounds__(256) void transconv_k(const float* __restrict__ in,
                                                   short* __restrict__ out,
                                                   int R, int C, int ldo) {
    __shared__ float t[32][33];
    const int r0 = blockIdx.y * 32, c0 = blockIdx.x * 32;
    const int tx = threadIdx.x, ty = threadIdx.y;
#pragma unroll
    for (int i = 0; i < 4; ++i)
        t[ty * 4 + i][tx] = in[(size_t)(r0 + ty * 4 + i) * C + c0 + tx];
    __syncthreads();
#pragma unroll
    for (int i = 0; i < 4; ++i)
        out[(size_t)(c0 + ty * 4 + i) * ldo + r0 + tx] = f2bf(t[tx][ty * 4 + i]);
}

// ---------------------------------------------------------------------------
// MoE weight transpose with row permutation for the grouped-A' layout
// ---------------------------------------------------------------------------
__global__ __launch_bounds__(256) void transconv_moe_k(const float* __restrict__ in,
                                                       short* __restrict__ out, int C) {
    __shared__ float t[32][33];
    const int r0 = blockIdx.y * 32, c0 = blockIdx.x * 32;
    const int tx = threadIdx.x, ty = threadIdx.y;
#pragma unroll
    for (int i = 0; i < 4; ++i)
        t[ty * 4 + i][tx] = in[(size_t)(r0 + ty * 4 + i) * C + c0 + tx];
    __syncthreads();
    const int e = r0 / 1408, k = r0 - e * 1408;
    const int rp0 = (k < 384) ? (e * 384 + k) : (1536 + e * 1024 + (k - 384));
#pragma unroll
    for (int i = 0; i < 4; ++i)
        out[(size_t)(c0 + ty * 4 + i) * 5632 + rp0 + tx] = f2bf(t[tx][ty * 4 + i]);
}

// ---------------------------------------------------------------------------
// Pipelined GEMM (R16 optimum): BM x 128 tile, BK=64, 512 threads = 8 waves
// 4Mx2N, 16x16x32 MFMA, A x3 / B x2 LDS, counted vmcnt, setprio, XOR(row&7)
// swizzle (0 conflicts), 2 barriers/iter (PH1 barrier staggers wave phases —
// removing it regressed 5% in R17).
// BM=128: per-wave 32x64, 80 KB LDS -> 2 blocks/CU (4 waves/SIMD).
// EPI: 0 = +bias -> bf16   1 = +bias, leaky -> bf16
//      5 = +coeff@bias, leaky, 4 coeff-scaled bf16 copies at e*1024 (MoE)
//      6 = +coeff@bias, no act -> f32 (MoE last layer)
//      7 = split-K partial: raw f32 accumulate -> Cf + z*BATCH*ldc; the
//          K-offset is blockIdx.z*K (grid.z = number of K slices). (R19)
// ---------------------------------------------------------------------------
template <int BM, int EPI>
__global__ __launch_bounds__(512) void mm_p3(
    const short* __restrict__ A, int lda,
    const short* __restrict__ Bt, int ldb,
    const float* __restrict__ bias, const float* __restrict__ coeff,
    short* __restrict__ Cb, float* __restrict__ Cf, int ldc, int N, int K) {
    constexpr int TSZA = BM * 64;   // shorts per A buffer
    constexpr int TSZB = 128 * 64;  // shorts per B buffer (16 KB)
    constexpr int RA = BM / 64;     // stageA rounds == vmcnt count
    constexpr int WMR = BM / 4;     // per-wave M rows
    constexpr int FM = WMR / 16;    // a-fragments per wave
    __shared__ short As[3 * TSZA];
    __shared__ short Bs[2 * TSZB];
    const int tid = threadIdx.x;
    const int wave = tid >> 6, lane = tid & 63;
    const int wm = wave >> 1, wq = wave & 1;  // 4 M-waves x 2 N-waves

    // split-K column offset (EPI 7 only; grid.z slices of width K)
    if constexpr (EPI == 7) {
        const int kz = blockIdx.z * K;
        A += kz;
        Bt += kz;
    }

    // XCD-aware swizzle (bijective when nwg%8==0; per z-slice)
    int bx = blockIdx.x, by = blockIdx.y;
    {
        int nwg = gridDim.x * gridDim.y;
        if ((nwg & 7) == 0) {
            int flat = by * gridDim.x + bx;
            int nf = (flat & 7) * (nwg >> 3) + (flat >> 3);
            bx = nf % gridDim.x;
            by = nf / gridDim.x;
        }
    }
    const int m0 = by * BM, n0 = bx * 128;
    const int srow = lane >> 3;                   // 0..7 within 8-row chunk
    const int scolsw = ((lane & 7) ^ srow) << 3;  // swizzled source col (shorts)
    const int l15 = lane & 15;
    const int khalf = (lane >> 4) << 3;

    auto stageA = [&](int kt, int buf) {
#pragma unroll
        for (int it = 0; it < RA; ++it) {
            int chunk = it * 8 + wave;
            int row = chunk * 8 + srow;
            const short* g = A + (size_t)(m0 + row) * lda + kt + scolsw;
            __builtin_amdgcn_global_load_lds(
                (const __attribute__((address_space(1))) void*)g,
                (__attribute__((address_space(3))) void*)(As + buf * TSZA + chunk * 512),
                16, 0, 0);
        }
    };
    auto stageB = [&](int kt, int buf) {
#pragma unroll
        for (int it = 0; it < 2; ++it) {
            int chunk = it * 8 + wave;
            int row = chunk * 8 + srow;
            const short* g = Bt + (size_t)(n0 + row) * ldb + kt + scolsw;
            __builtin_amdgcn_global_load_lds(
                (const __attribute__((address_space(1))) void*)g,
                (__attribute__((address_space(3))) void*)(Bs + buf * TSZB + chunk * 512),
                16, 0, 0);
        }
    };
    auto waitRA = [&]() {
        if constexpr (BM == 256) {
            asm volatile("s_waitcnt vmcnt(4)" ::: "memory");
        } else {
            asm volatile("s_waitcnt vmcnt(2)" ::: "memory");
        }
    };

    f32x4 acc[FM][4];
    const f32x4 z4 = {0.f, 0.f, 0.f, 0.f};
#pragma unroll
    for (int i = 0; i < FM; ++i)
#pragma unroll
        for (int j = 0; j < 4; ++j) acc[i][j] = z4;

    const int nk = K >> 6;  // all call sites have nk >= 3

    // prologue: A(0),B(0),A(1) in flight; wait A(0),B(0), leave A(1)
    stageA(0, 0);
    stageB(0, 0);
    stageA(64, 1);
    __builtin_amdgcn_sched_barrier(0);
    waitRA();
    __builtin_amdgcn_s_barrier();
    __builtin_amdgcn_sched_barrier(0);

    int ia = 0;  // A buffer holding tile t
    int is = 2;  // A buffer for tile t+2
#pragma unroll 1
    for (int t = 0; t < nk; ++t) {
        const short* Ah = As + ia * TSZA;
        const short* Bh = Bs + (t & 1) * TSZB;

        // ---- PH1 (kk=0): ds_read + stageB(t+1) -> MFMA -> barrier ----
        {
            bf16x8 a[FM], b[4];
#pragma unroll
            for (int i = 0; i < FM; ++i) {
                int R = wm * WMR + i * 16 + l15;
                a[i] = *(const bf16x8*)&Ah[R * 64 + (khalf ^ ((R & 7) << 3))];
            }
#pragma unroll
            for (int j = 0; j < 4; ++j) {
                int R = wq * 64 + j * 16 + l15;
                b[j] = *(const bf16x8*)&Bh[R * 64 + (khalf ^ ((R & 7) << 3))];
            }
            if (t + 1 < nk) stageB((t + 1) << 6, (t + 1) & 1);
            __builtin_amdgcn_sched_barrier(0);
            __builtin_amdgcn_s_setprio(1);
#pragma unroll
            for (int i = 0; i < FM; ++i)
#pragma unroll
                for (int j = 0; j < 4; ++j)
                    acc[i][j] = __builtin_amdgcn_mfma_f32_16x16x32_bf16(
                        a[i], b[j], acc[i][j], 0, 0, 0);
            __builtin_amdgcn_s_setprio(0);
            __builtin_amdgcn_sched_barrier(0);
            __builtin_amdgcn_s_barrier();  // phase stagger across waves (perf!)
        }

        // ---- PH2 (kk=1): ds_read + stageA(t+2) -> MFMA -> vmcnt -> barrier ----
        {
            bf16x8 a[FM], b[4];
#pragma unroll
            for (int i = 0; i < FM; ++i) {
                int R = wm * WMR + i * 16 + l15;
                a[i] = *(const bf16x8*)&Ah[R * 64 + ((32 + khalf) ^ ((R & 7) << 3))];
            }
#pragma unroll
            for (int j = 0; j < 4; ++j) {
                int R = wq * 64 + j * 16 + l15;
                b[j] = *(const bf16x8*)&Bh[R * 64 + ((32 + khalf) ^ ((R & 7) << 3))];
            }
            if (t + 2 < nk) stageA((t + 2) << 6, is);
            __builtin_amdgcn_sched_barrier(0);
            __builtin_amdgcn_s_setprio(1);
#pragma unroll
            for (int i = 0; i < FM; ++i)
#pragma unroll
                for (int j = 0; j < 4; ++j)
                    acc[i][j] = __builtin_amdgcn_mfma_f32_16x16x32_bf16(
                        a[i], b[j], acc[i][j], 0, 0, 0);
            __builtin_amdgcn_s_setprio(0);
            __builtin_amdgcn_sched_barrier(0);
            if (t + 1 < nk) {
                if (t + 2 < nk) {
                    waitRA();  // A(t+1),B(t+1) landed; A(t+2) stays in flight
                } else {
                    asm volatile("s_waitcnt vmcnt(0)" ::: "memory");
                }
            }
            __builtin_amdgcn_s_barrier();  // buffer-rotation fence (required)
        }
        ia = (ia == 2) ? 0 : ia + 1;
        is = (is == 2) ? 0 : is + 1;
    }

    // epilogue: D layout col=lane&15, row=(lane>>4)*4+reg
    const size_t zbase = (EPI == 7) ? (size_t)blockIdx.z * BATCH * ldc : 0;
#pragma unroll
    for (int i = 0; i < FM; ++i) {
#pragma unroll
        for (int r = 0; r < 4; ++r) {
            int row = m0 + wm * WMR + i * 16 + ((lane >> 4) << 2) + r;
#pragma unroll
            for (int j = 0; j < 4; ++j) {
                int col = n0 + wq * 64 + j * 16 + l15;
                float v = acc[i][j][r];
                if constexpr (EPI == 0) {
                    v += bias[col];
                    Cb[(size_t)row * ldc + col] = f2bf(v);
                } else if constexpr (EPI == 1) {
                    v = leakyf(v + bias[col]);
                    Cb[(size_t)row * ldc + col] = f2bf(v);
                } else if constexpr (EPI == 5) {
                    const float4 c4 = *reinterpret_cast<const float4*>(coeff + (size_t)row * 4);
                    v += c4.x * bias[col] + c4.y * bias[N + col] +
                         c4.z * bias[2 * N + col] + c4.w * bias[3 * N + col];
                    float a = leakyf(v);
                    Cb[(size_t)row * ldc + 0 * 1024 + col] = f2bf(c4.x * a);
                    Cb[(size_t)row * ldc + 1 * 1024 + col] = f2bf(c4.y * a);
                    Cb[(size_t)row * ldc + 2 * 1024 + col] = f2bf(c4.z * a);
                    Cb[(size_t)row * ldc + 3 * 1024 + col] = f2bf(c4.w * a);
                } else if constexpr (EPI == 6) {
                    const float4 c4 = *reinterpret_cast<const float4*>(coeff + (size_t)row * 4);
                    v += c4.x * bias[col] + c4.y * bias[N + col] +
                         c4.z * bias[2 * N + col] + c4.w * bias[3 * N + col];
                    Cf[(size_t)row * ldc + col] = v;
                } else {  // EPI == 7: raw split-K partial
                    Cf[zbase + (size_t)row * ldc + col] = v;
                }
            }
        }
    }
}

// ---------------------------------------------------------------------------
// bf16 MFMA GEMM (kept for heads/gate/SAFE): 128-tile, BK=64, dbuf + XOR
// swizzle, 16x16x32. EPI: 1 leaky bf16; 2 heads; 3/4 MoE expert loop.
// ---------------------------------------------------------------------------
template <int BM, int BN, int EPI>
__global__ __launch_bounds__(256) void mm_k(
    const short* __restrict__ A, int lda,
    const short* __restrict__ Bt, int ldb,
    const float* __restrict__ bias, const float* __restrict__ bias2,
    const float* __restrict__ coeff,
    short* __restrict__ Cb, float* __restrict__ Cf, float* __restrict__ Cf2,
    int ldc, int N, int K) {
    constexpr bool MOE = (EPI == 3 || EPI == 4);
    constexpr int WM = BM / 2, WN = BN / 2;
    constexpr int FM = WM / 16, FN = WN / 16;
    constexpr int ASZ = BM * 64, BSZ = BN * 64;
    __shared__ short As[2 * ASZ];
    __shared__ short Bs[2 * BSZ];
    const int tid = threadIdx.x;
    const int wave = tid >> 6, lane = tid & 63;
    const int wm = wave >> 1, wq = wave & 1;

    int bx = blockIdx.x, by = blockIdx.y;
    {
        int nwg = gridDim.x * gridDim.y;
        if ((nwg & 7) == 0) {
            int flat = by * gridDim.x + bx;
            int nf = (flat & 7) * (nwg >> 3) + (flat >> 3);
            bx = nf % gridDim.x;
            by = nf / gridDim.x;
        }
    }
    const int m0 = by * BM, n0 = bx * BN;
    const int srow = lane >> 3;
    const int scolsw = ((lane & 7) ^ srow) << 3;
    const int l15 = lane & 15;
    const int khalf = (lane >> 4) << 3;

    auto stage = [&](const short* Bsrc, int kt, int half) {
#pragma unroll
        for (int it = 0; it < BM / 32; ++it) {
            int chunk = it * 4 + wave;
            int row = chunk * 8 + srow;
            const short* g = A + (size_t)(m0 + row) * lda + kt + scolsw;
            __builtin_amdgcn_global_load_lds(
                (const __attribute__((address_space(1))) void*)g,
                (__attribute__((address_space(3))) void*)(As + half * ASZ + chunk * 512),
                16, 0, 0);
        }
#pragma unroll
        for (int it = 0; it < BN / 32; ++it) {
            int chunk = it * 4 + wave;
            int row = chunk * 8 + srow;
            const short* g = Bsrc + (size_t)(n0 + row) * ldb + kt + scolsw;
            __builtin_amdgcn_global_load_lds(
                (const __attribute__((address_space(1))) void*)g,
                (__attribute__((address_space(3))) void*)(Bs + half * BSZ + chunk * 512),
                16, 0, 0);
        }
    };

    f32x4 acc[FM][FN];
    f32x4 accf[MOE ? FM : 1][MOE ? FN : 1];
    const f32x4 z4 = {0.f, 0.f, 0.f, 0.f};
    if constexpr (MOE) {
#pragma unroll
        for (int i = 0; i < FM; ++i)
#pragma unroll
            for (int j = 0; j < FN; ++j) accf[i][j] = z4;
    }

    constexpr int NE = MOE ? 4 : 1;
    const int nk = K >> 6;
#pragma unroll 1
    for (int e = 0; e < NE; ++e) {
        const short* Be = Bt + (size_t)e * K;
#pragma unroll
        for (int i = 0; i < FM; ++i)
#pragma unroll
            for (int j = 0; j < FN; ++j) acc[i][j] = z4;

        stage(Be, 0, 0);
        __syncthreads();

#pragma unroll 1
        for (int t = 0; t < nk; ++t) {
            const int cur = t & 1;
            if (t + 1 < nk) stage(Be, (t + 1) << 6, cur ^ 1);
            const short* Ah = As + cur * ASZ;
            const short* Bh = Bs + cur * BSZ;
#pragma unroll
            for (int kk = 0; kk < 2; ++kk) {
                bf16x8 a[FM], b[FN];
#pragma unroll
                for (int i = 0; i < FM; ++i) {
                    int R = wm * WM + i * 16 + l15;
                    int off = (kk * 32 + khalf) ^ ((R & 7) << 3);
                    a[i] = *(const bf16x8*)&Ah[R * 64 + off];
                }
#pragma unroll
                for (int j = 0; j < FN; ++j) {
                    int R = wq * WN + j * 16 + l15;
                    int off = (kk * 32 + khalf) ^ ((R & 7) << 3);
                    b[j] = *(const bf16x8*)&Bh[R * 64 + off];
                }
#pragma unroll
                for (int i = 0; i < FM; ++i)
#pragma unroll
                    for (int j = 0; j < FN; ++j)
                        acc[i][j] = __builtin_amdgcn_mfma_f32_16x16x32_bf16(
                            a[i], b[j], acc[i][j], 0, 0, 0);
            }
            __syncthreads();
        }
        if constexpr (MOE) {
#pragma unroll
            for (int i = 0; i < FM; ++i) {
                int rbase = m0 + wm * WM + i * 16 + ((lane >> 4) << 2);
#pragma unroll
                for (int r = 0; r < 4; ++r) {
                    float ce = coeff[(size_t)(rbase + r) * 4 + e];
#pragma unroll
                    for (int j = 0; j < FN; ++j) accf[i][j][r] += ce * acc[i][j][r];
                }
            }
        }
    }

#pragma unroll
    for (int i = 0; i < FM; ++i) {
#pragma unroll
        for (int r = 0; r < 4; ++r) {
            int row = m0 + wm * WM + i * 16 + ((lane >> 4) << 2) + r;
#pragma unroll
            for (int j = 0; j < FN; ++j) {
                int col = n0 + wq * WN + j * 16 + l15;
                float v = MOE ? accf[i][j][r] : acc[i][j][r];
                if constexpr (EPI == 0) {
                    v += bias[col];
                    Cb[(size_t)row * ldc + col] = f2bf(v);
                } else if constexpr (EPI == 1) {
                    v = leakyf(v + bias[col]);
                    Cb[(size_t)row * ldc + col] = f2bf(v);
                } else if constexpr (EPI == 2) {
                    if (col < 128) {
                        Cf[(size_t)row * 128 + col] = v + bias[col];
                    } else {
                        float u = v + bias2[col - 128];
                        u = fminf(fmaxf(u, -5.f), 5.f);
                        Cf2[(size_t)row * 128 + (col - 128)] = u;
                    }
                } else if constexpr (EPI == 3) {
                    const float* c4 = coeff + (size_t)row * 4;
                    v += c4[0] * bias[col] + c4[1] * bias[N + col] +
                         c4[2] * bias[2 * N + col] + c4[3] * bias[3 * N + col];
                    Cb[(size_t)row * ldc + col] = f2bf(leakyf(v));
                } else {  // EPI == 4
                    const float* c4 = coeff + (size_t)row * 4;
                    v += c4[0] * bias[col] + c4[1] * bias[N + col] +
                         c4[2] * bias[2 * N + col] + c4[3] * bias[3 * N + col];
                    Cf[(size_t)row * ldc + col] = v;
                }
            }
        }
    }
}

// ---------------------------------------------------------------------------
// normalize + scatter bf16 into cat buffers
// ---------------------------------------------------------------------------
__global__ __launch_bounds__(256) void norm_k(
    const float* __restrict__ x, const float* __restrict__ w,
    const float* __restrict__ im, const float* __restrict__ iv,
    const float* __restrict__ cm, const float* __restrict__ cv,
    short* __restrict__ enc0, short* __restrict__ encA,
    short* __restrict__ encB, short* __restrict__ dec0) {
    int idx = blockIdx.x * 256 + threadIdx.x;
    const int TX = BATCH * 512;
    if (idx < TX) {
        int b = idx >> 9, j = idx & 511;
        float v = (x[idx] - im[j]) * rsqrtf(iv[j] + 1e-4f);
        v = fminf(fmaxf(v, -5.f), 5.f);
        enc0[(size_t)b * 768 + j] = f2bf(v);
    } else {
        int k = idx - TX;
        if (k < BATCH * 256) {
            int b = k >> 8, j = k & 255;
            float v = (w[k] - cm[j]) * rsqrtf(cv[j] + 1e-4f);
            if (v != v) v = 0.f;  // isnan -> 0 (wn only)
            v = fminf(fmaxf(v, -5.f), 5.f);
            short s = f2bf(v);
            enc0[(size_t)b * 768 + 512 + j] = s;
            encA[(size_t)b * 1280 + j] = s;
            encB[(size_t)b * 1280 + j] = s;
            dec0[(size_t)b * 384 + 128 + j] = s;
        }
    }
}

__global__ __launch_bounds__(256) void reparam_k(
    const float* __restrict__ mu, const float* __restrict__ lv,
    const float* __restrict__ eps, float* __restrict__ z, short* __restrict__ dec0) {
    int idx = blockIdx.x * 256 + threadIdx.x;
    if (idx >= BATCH * 128) return;
    float zv = mu[idx] + eps[idx] * expf(0.5f * lv[idx]);
    z[idx] = zv;
    int b = idx >> 7, j = idx & 127;
    dec0[(size_t)b * 384 + j] = f2bf(zv);
}

__global__ __launch_bounds__(256) void fill_zc_k(const short* __restrict__ dec0,
                                                 const float* __restrict__ cf,
                                                 short* __restrict__ dA,
                                                 short* __restrict__ dB) {
    int idx = blockIdx.x * 256 + threadIdx.x;
    if (idx >= BATCH * 1536) return;
    int b = idx / 1536, c = idx - b * 1536;
    int e = c / 384, k = c - e * 384;
    short s = f2bf(cf[(size_t)b * 4 + e] * bf2f(dec0[(size_t)b * 384 + k]));
    dA[(size_t)b * 5632 + c] = s;
    dB[(size_t)b * 5632 + c] = s;
}

__global__ __launch_bounds__(256) void fill_dec_k(const short* __restrict__ dec0,
                                                  short* __restrict__ decA,
                                                  short* __restrict__ decB) {
    int idx = blockIdx.x * 256 + threadIdx.x;
    if (idx >= BATCH * 384) return;
    int b = idx / 384, c = idx - b * 384;
    short s = dec0[idx];
    decA[(size_t)b * 1408 + c] = s;
    decB[(size_t)b * 1408 + c] = s;
}

// R19: dec4 split-K reduce: y = p[z=0] + p[z=1] + coeff @ b4
__global__ __launch_bounds__(256) void dec4_red_k(const float* __restrict__ p,
                                                  const float* __restrict__ cf,
                                                  const float* __restrict__ b4,
                                                  float* __restrict__ y) {
    int idx = blockIdx.x * 256 + threadIdx.x;
    if (idx >= BATCH * 512) return;
    int b = idx >> 9, c = idx & 511;
    const float4 c4 = *reinterpret_cast<const float4*>(cf + (size_t)b * 4);
    float v = p[idx] + p[(size_t)BATCH * 512 + idx];
    v += c4.x * b4[c] + c4.y * b4[512 + c] + c4.z * b4[1024 + c] + c4.w * b4[1536 + c];
    y[idx] = v;
}

__global__ __launch_bounds__(256) void gate_sm_k(const short* __restrict__ g1,
                                                 const float* __restrict__ w2,
                                                 const float* __restrict__ b2,
                                                 float* __restrict__ coeff) {
    int r = blockIdx.x * 256 + threadIdx.x;
    if (r >= BATCH) return;
    float l0 = b2[0], l1 = b2[1], l2 = b2[2], l3 = b2[3];
    const short* row = g1 + (size_t)r * 64;
#pragma unroll
    for (int k = 0; k < 64; ++k) {
        float gv = bf2f(row[k]);
        l0 += gv * w2[k * 4 + 0];
        l1 += gv * w2[k * 4 + 1];
        l2 += gv * w2[k * 4 + 2];
        l3 += gv * w2[k * 4 + 3];
    }
    float mx = fmaxf(fmaxf(l0, l1), fmaxf(l2, l3));
    float e0 = expf(l0 - mx), e1 = expf(l1 - mx), e2 = expf(l2 - mx), e3 = expf(l3 - mx);
    float s = 1.f / (e0 + e1 + e2 + e3);
    float4 outv = make_float4(e0 * s, e1 * s, e2 * s, e3 * s);
    *reinterpret_cast<float4*>(coeff + (size_t)r * 4) = outv;
}

extern "C" void kernel_launch(void* const* d_in, const int* in_sizes, int n_in,
                              void* d_out, int out_size, void* d_ws, size_t ws_size,
                              hipStream_t stream) {
    const float* x    = (const float*)d_in[0];
    const float* w    = (const float*)d_in[1];
    const float* epsv = (const float*)d_in[2];
    const float* rim  = (const float*)d_in[3];
    const float* riv  = (const float*)d_in[4];
    const float* rcm  = (const float*)d_in[5];
    const float* rcv  = (const float*)d_in[6];
    const float* ew0 = (const float*)d_in[7];  const float* eb0 = (const float*)d_in[8];
    const float* ew1 = (const float*)d_in[9];  const float* eb1 = (const float*)d_in[10];
    const float* ew2 = (const float*)d_in[11]; const float* eb2 = (const float*)d_in[12];
    const float* ew3 = (const float*)d_in[13]; const float* eb3 = (const float*)d_in[14];
    const float* muw = (const float*)d_in[15]; const float* mub = (const float*)d_in[16];
    const float* lvw = (const float*)d_in[17]; const float* lvb = (const float*)d_in[18];
    const float* gw0 = (const float*)d_in[19]; const float* gb0 = (const float*)d_in[20];
    const float* gw1 = (const float*)d_in[21]; const float* gb1 = (const float*)d_in[22];
    const float* gw2 = (const float*)d_in[23]; const float* gb2 = (const float*)d_in[24];
    const float* dw0 = (const float*)d_in[25]; const float* db0 = (const float*)d_in[26];
    const float* dw1 = (const float*)d_in[27]; const float* db1 = (const float*)d_in[28];
    const float* dw2 = (const float*)d_in[29]; const float* db2 = (const float*)d_in[30];
    const float* dw3 = (const float*)d_in[31]; const float* db3 = (const float*)d_in[32];
    const float* dw4 = (const float*)d_in[33]; const float* db4 = (const float*)d_in[34];

    float* out    = (float*)d_out;
    float* z_out  = out;                          // [B,128]
    float* y_out  = out + (size_t)BATCH * 128;    // [B,512]
    float* mu_out = out + (size_t)BATCH * 640;    // [B,128]
    float* lv_out = out + (size_t)BATCH * 768;    // [B,128]

    // ---- workspace carve ----
    char* cur = (char*)d_ws;
    auto alloc = [&](size_t bytes) -> char* {
        char* p = cur;
        cur += (bytes + 255) & ~(size_t)255;
        return p;
    };
    auto align256 = [](size_t b) { return (b + 255) & ~(size_t)255; };

    short* ew0t = (short*)alloc((size_t)768 * 1024 * 2);
    short* ew1t = (short*)alloc((size_t)1280 * 1024 * 2);
    short* ew2t = (short*)alloc((size_t)1280 * 1024 * 2);
    short* ew3t = (short*)alloc((size_t)1280 * 1024 * 2);
    short* hdWt = (short*)alloc((size_t)256 * 1024 * 2);   // rows 0-127 mu, 128-255 lv
    short* gw0t = (short*)alloc((size_t)64 * 384 * 2);
    short* gw1t = (short*)alloc((size_t)64 * 64 * 2);
    short* dw0t = (short*)alloc((size_t)1024 * 1536 * 2);
    short* dw1t = (short*)alloc((size_t)1024 * 5632 * 2);
    short* dw2t = (short*)alloc((size_t)1024 * 5632 * 2);
    short* dw3t = (short*)alloc((size_t)1024 * 5632 * 2);
    short* dw4t = (short*)alloc((size_t)512 * 5632 * 2);
    short* dec0 = (short*)alloc((size_t)BATCH * 384 * 2);  // [z|wn]
    short* g0   = (short*)alloc((size_t)BATCH * 64 * 2);
    short* g1   = (short*)alloc((size_t)BATCH * 64 * 2);
    float* cf   = (float*)alloc((size_t)BATCH * 4 * 4);

    char* region = cur;
    const size_t bigA = align256((size_t)BATCH * 5632 * 2);     // 92.3 MB
    const size_t fastNeed = (size_t)(region - (char*)d_ws) + 2 * bigA;
    const bool fast = (ws_size >= fastNeed);

    short* enc0 = (short*)region;                                           // [B,768]
    short* encA = (short*)(region + align256((size_t)BATCH * 768 * 2));     // [B,1280]
    short* encB = (short*)((char*)encA + align256((size_t)BATCH * 1280 * 2)); // [B,1280]
    short* hl   = encB;                                                     // [B,1024]
    short* dAp = (short*)region;
    short* dBp = (short*)(region + bigA);
    float* d4p = (float*)dAp;  // dec4 split-K partials [2][B][512] alias dAp (dead after dec3)
    short* decA = (short*)region;                                           // [B,1408]
    short* decB = (short*)(region + align256((size_t)BATCH * 1408 * 2));    // [B,1408]

    dim3 blk(256);
    dim3 blk5(512);
    dim3 tblk(32, 8);

    // ---- weight transpose+convert ----
    transconv_k<<<dim3(1024 / 32, 768 / 32), tblk, 0, stream>>>(ew0, ew0t, 768, 1024, 768);
    transconv_k<<<dim3(1024 / 32, 1280 / 32), tblk, 0, stream>>>(ew1, ew1t, 1280, 1024, 1280);
    transconv_k<<<dim3(1024 / 32, 1280 / 32), tblk, 0, stream>>>(ew2, ew2t, 1280, 1024, 1280);
    transconv_k<<<dim3(1024 / 32, 1280 / 32), tblk, 0, stream>>>(ew3, ew3t, 1280, 1024, 1280);
    transconv_k<<<dim3(128 / 32, 1024 / 32), tblk, 0, stream>>>(muw, hdWt, 1024, 128, 1024);
    transconv_k<<<dim3(128 / 32, 1024 / 32), tblk, 0, stream>>>(lvw, hdWt + (size_t)128 * 1024, 1024, 128, 1024);
    transconv_k<<<dim3(64 / 32, 384 / 32), tblk, 0, stream>>>(gw0, gw0t, 384, 64, 384);
    transconv_k<<<dim3(64 / 32, 64 / 32), tblk, 0, stream>>>(gw1, gw1t, 64, 64, 64);
    transconv_k<<<dim3(1024 / 32, 1536 / 32), tblk, 0, stream>>>(dw0, dw0t, 1536, 1024, 1536);
    if (fast) {
        transconv_moe_k<<<dim3(1024 / 32, 5632 / 32), tblk, 0, stream>>>(dw1, dw1t, 1024);
        transconv_moe_k<<<dim3(1024 / 32, 5632 / 32), tblk, 0, stream>>>(dw2, dw2t, 1024);
        transconv_moe_k<<<dim3(1024 / 32, 5632 / 32), tblk, 0, stream>>>(dw3, dw3t, 1024);
        transconv_moe_k<<<dim3(512 / 32, 5632 / 32), tblk, 0, stream>>>(dw4, dw4t, 512);
    } else {
        transconv_k<<<dim3(1024 / 32, 5632 / 32), tblk, 0, stream>>>(dw1, dw1t, 5632, 1024, 5632);
        transconv_k<<<dim3(1024 / 32, 5632 / 32), tblk, 0, stream>>>(dw2, dw2t, 5632, 1024, 5632);
        transconv_k<<<dim3(1024 / 32, 5632 / 32), tblk, 0, stream>>>(dw3, dw3t, 5632, 1024, 5632);
        transconv_k<<<dim3(512 / 32, 5632 / 32), tblk, 0, stream>>>(dw4, dw4t, 5632, 512, 5632);
    }

    // ---- normalize into cat buffers ----
    norm_k<<<dim3(BATCH * 768 / 256), blk, 0, stream>>>(x, w, rim, riv, rcm, rcv,
                                                        enc0, encA, encB, dec0);

    // ---- encoder (BM=128, 8 waves, 2 blocks/CU = 4 waves/SIMD) ----
    dim3 gBig(1024 / 128, BATCH / 128);  // 8 x 64 = 512 blocks, 2/CU
    mm_p3<128, 0><<<gBig, blk5, 0, stream>>>(enc0, 768, ew0t, 768, eb0, nullptr,
                                             encA + 256, nullptr, 1280, 1024, 768);
    mm_p3<128, 0><<<gBig, blk5, 0, stream>>>(encA, 1280, ew1t, 1280, eb1, nullptr,
                                             encB + 256, nullptr, 1280, 1024, 1280);
    mm_p3<128, 0><<<gBig, blk5, 0, stream>>>(encB, 1280, ew2t, 1280, eb2, nullptr,
                                             encA + 256, nullptr, 1280, 1024, 1280);
    mm_p3<128, 1><<<gBig, blk5, 0, stream>>>(encA, 1280, ew3t, 1280, eb3, nullptr,
                                             hl, nullptr, 1024, 1024, 1280);

    // ---- heads: mu | clip(lv) ----
    mm_k<64, 128, 2><<<dim3(2, BATCH / 64), blk, 0, stream>>>(hl, 1024, hdWt, 1024, mub, lvb,
                                                              nullptr, nullptr, mu_out, lv_out,
                                                              0, 256, 1024);

    reparam_k<<<dim3(BATCH * 128 / 256), blk, 0, stream>>>(mu_out, lv_out, epsv, z_out, dec0);

    // ---- gate ----
    mm_k<64, 64, 1><<<dim3(1, BATCH / 64), blk, 0, stream>>>(dec0, 384, gw0t, 384, gb0, nullptr,
                                                             nullptr, g0, nullptr, nullptr,
                                                             64, 64, 384);
    mm_k<64, 64, 1><<<dim3(1, BATCH / 64), blk, 0, stream>>>(g0, 64, gw1t, 64, gb1, nullptr,
                                                             nullptr, g1, nullptr, nullptr,
                                                             64, 64, 64);
    gate_sm_k<<<dim3(BATCH / 256), blk, 0, stream>>>(g1, gw2, gb2, cf);

    if (fast) {
        // ---- FAST decoder: single-GEMM MoE layers (BM=128, 2 blocks/CU) ----
        fill_zc_k<<<dim3(BATCH * 1536 / 256), blk, 0, stream>>>(dec0, cf, dAp, dBp);
        mm_p3<128, 5><<<gBig, blk5, 0, stream>>>(dAp, 5632, dw0t, 1536, db0, cf,
                                                 dAp + 1536, nullptr, 5632, 1024, 1536);
        mm_p3<128, 5><<<gBig, blk5, 0, stream>>>(dAp, 5632, dw1t, 5632, db1, cf,
                                                 dBp + 1536, nullptr, 5632, 1024, 5632);
        mm_p3<128, 5><<<gBig, blk5, 0, stream>>>(dBp, 5632, dw2t, 5632, db2, cf,
                                                 dAp + 1536, nullptr, 5632, 1024, 5632);
        mm_p3<128, 5><<<gBig, blk5, 0, stream>>>(dAp, 5632, dw3t, 5632, db3, cf,
                                                 dBp + 1536, nullptr, 5632, 1024, 5632);
        // dec4: split-K 2 (grid.z=2 -> 512 blocks = 2 blocks/CU) into fp32
        // partials (alias dAp, dead after dec3), then deterministic reduce.
        mm_p3<128, 7><<<dim3(512 / 128, BATCH / 128, 2), blk5, 0, stream>>>(
            dBp, 5632, dw4t, 5632, nullptr, nullptr, nullptr, d4p, 512, 512, 2816);
        dec4_red_k<<<dim3(BATCH * 512 / 256), blk, 0, stream>>>(d4p, cf, db4, y_out);
    } else {
        // ---- SAFE decoder: expert-loop kernels ----
        fill_dec_k<<<dim3(BATCH * 384 / 256), blk, 0, stream>>>(dec0, decA, decB);
        dim3 gDec(1024 / 128, BATCH / 128);
        mm_k<128, 128, 3><<<gDec, blk, 0, stream>>>(dec0, 384, dw0t, 1536, db0, nullptr, cf,
                                                    decA + 384, nullptr, nullptr, 1408, 1024, 384);
        mm_k<128, 128, 3><<<gDec, blk, 0, stream>>>(decA, 1408, dw1t, 5632, db1, nullptr, cf,
                                                    decB + 384, nullptr, nullptr, 1408, 1024, 1408);
        mm_k<128, 128, 3><<<gDec, blk, 0, stream>>>(decB, 1408, dw2t, 5632, db2, nullptr, cf,
                                                    decA + 384, nullptr, nullptr, 1408, 1024, 1408);
        mm_k<128, 128, 3><<<gDec, blk, 0, stream>>>(decA, 1408, dw3t, 5632, db3, nullptr, cf,
                                                    decB + 384, nullptr, nullptr, 1408, 1024, 1408);
        mm_k<128, 128, 4><<<dim3(512 / 128, BATCH / 128), blk, 0, stream>>>(
            decB, 1408, dw4t, 5632, db4, nullptr, cf, nullptr, y_out, nullptr, 512, 512, 1408);
    }
}